// Round 1
// baseline (2180.166 us; speedup 1.0000x reference)
//
#include <hip/hip_runtime.h>
#include <stdint.h>

#define HD 64
#define BN_EPS 1e-5f

// ---------------- init / histogram ----------------

__global__ __launch_bounds__(256)
void k_init(int* __restrict__ cnt, float* __restrict__ deg, float* __restrict__ cutpad,
            int* __restrict__ gstart, int n, int B) {
    int i = blockIdx.x * 256 + threadIdx.x;
    if (i < n) { cnt[i] = 0; deg[i] = 0.f; }
    if (i < 2048) cutpad[i] = 0.f;
    if (i <= B) gstart[i] = n;  // sentinel
}

__global__ __launch_bounds__(256)
void k_node_pre(const float* __restrict__ x, const int* __restrict__ batch,
                float* __restrict__ maskA, int* __restrict__ gstart, int n) {
    int i = blockIdx.x * 256 + threadIdx.x;
    if (i >= n) return;
    maskA[i] = (x[i] != 0.f) ? 1.f : 0.f;
    atomicMin(&gstart[batch[i]], i);
}

__global__ __launch_bounds__(256)
void k_count(const int* __restrict__ row, const int* __restrict__ col,
             const float* __restrict__ x, int* __restrict__ cnt,
             float* __restrict__ deg, float* __restrict__ maskA, int E) {
    int e = blockIdx.x * 256 + threadIdx.x;
    if (e >= E) return;
    int r = row[e], c = col[e];
    atomicAdd(&cnt[c], 1);
    atomicAdd(&deg[r], 1.0f);
    if (x[r] != 0.f) maskA[c] = 1.f;  // idempotent OR
}

// ---------------- prefix scan (3 passes) ----------------

__global__ __launch_bounds__(256)
void scan_pass1(const int* __restrict__ cnt, int* __restrict__ bsum, int n) {
    __shared__ int sd[256];
    int tid = threadIdx.x;
    int idx = blockIdx.x * 1024 + tid * 4;
    int4 v = make_int4(0, 0, 0, 0);
    if (idx + 3 < n) v = *(const int4*)(cnt + idx);
    else {
        if (idx     < n) v.x = cnt[idx];
        if (idx + 1 < n) v.y = cnt[idx + 1];
        if (idx + 2 < n) v.z = cnt[idx + 2];
        if (idx + 3 < n) v.w = cnt[idx + 3];
    }
    sd[tid] = v.x + v.y + v.z + v.w;
    __syncthreads();
    for (int o = 128; o > 0; o >>= 1) {
        if (tid < o) sd[tid] += sd[tid + o];
        __syncthreads();
    }
    if (tid == 0) bsum[blockIdx.x] = sd[0];
}

__global__ void scan_pass2(int* __restrict__ bsum, int nb, int* __restrict__ rowptr,
                           int n, int* __restrict__ gstart, int B) {
    // single thread: scan block sums + fix empty-graph starts
    int run = 0;
    for (int i = 0; i < nb; ++i) { int t = bsum[i]; bsum[i] = run; run += t; }
    rowptr[n] = run;
    gstart[B] = n;
    for (int b = B - 1; b >= 0; --b)
        if (gstart[b] > gstart[b + 1]) gstart[b] = gstart[b + 1];
}

__global__ __launch_bounds__(256)
void scan_pass3(int* __restrict__ cnt, const int* __restrict__ bsum,
                int* __restrict__ rowptr, int n) {
    __shared__ int sd[256];
    int tid = threadIdx.x;
    int idx = blockIdx.x * 1024 + tid * 4;
    int4 v = make_int4(0, 0, 0, 0);
    if (idx + 3 < n) v = *(const int4*)(cnt + idx);
    else {
        if (idx     < n) v.x = cnt[idx];
        if (idx + 1 < n) v.y = cnt[idx + 1];
        if (idx + 2 < n) v.z = cnt[idx + 2];
        if (idx + 3 < n) v.w = cnt[idx + 3];
    }
    int s = v.x + v.y + v.z + v.w;
    sd[tid] = s;
    __syncthreads();
    for (int o = 1; o < 256; o <<= 1) {
        int t = (tid >= o) ? sd[tid - o] : 0;
        __syncthreads();
        if (tid >= o) sd[tid] += t;
        __syncthreads();
    }
    int excl = sd[tid] - s + bsum[blockIdx.x];
    if (idx     < n) rowptr[idx]     = excl;
    if (idx + 1 < n) rowptr[idx + 1] = excl + v.x;
    if (idx + 2 < n) rowptr[idx + 2] = excl + v.x + v.y;
    if (idx + 3 < n) rowptr[idx + 3] = excl + v.x + v.y + v.z;
    // zero cnt for reuse as cursor
    if (idx + 3 < n) *(int4*)(cnt + idx) = make_int4(0, 0, 0, 0);
    else {
        if (idx     < n) cnt[idx]     = 0;
        if (idx + 1 < n) cnt[idx + 1] = 0;
        if (idx + 2 < n) cnt[idx + 2] = 0;
        if (idx + 3 < n) cnt[idx + 3] = 0;
    }
}

__global__ __launch_bounds__(256)
void csr_fill(const int* __restrict__ row, const int* __restrict__ col,
              const int* __restrict__ rowptr, int* __restrict__ cursor,
              int* __restrict__ srcs, int E) {
    int e = blockIdx.x * 256 + threadIdx.x;
    if (e >= E) return;
    int c = col[e];
    int pos = rowptr[c] + atomicAdd(&cursor[c], 1);
    srcs[pos] = row[e];
}

// ---------------- mask propagation ----------------

__global__ __launch_bounds__(256)
void k_mask_init(const float* __restrict__ src, float* __restrict__ dst, int n) {
    int i = blockIdx.x * 256 + threadIdx.x;
    if (i < n) dst[i] = (src[i] != 0.f) ? 1.f : 0.f;
}

__global__ __launch_bounds__(256)
void k_mask_or(const int* __restrict__ row, const int* __restrict__ col,
               const float* __restrict__ m, float* __restrict__ dst, int E) {
    int e = blockIdx.x * 256 + threadIdx.x;
    if (e >= E) return;
    if (m[row[e]] != 0.f) dst[col[e]] = 1.f;
}

// ---------------- gathers ----------------

__global__ __launch_bounds__(256)
void k_gather_s(const float* __restrict__ x, const int* __restrict__ rowptr,
                const int* __restrict__ srcs, float* __restrict__ aggs, int n) {
    int i = blockIdx.x * 256 + threadIdx.x;
    if (i >= n) return;
    float acc = x[i];
    int s = rowptr[i], e = rowptr[i + 1];
    int p = s;
    for (; p + 4 <= e; p += 4) {
        int j0 = srcs[p], j1 = srcs[p + 1], j2 = srcs[p + 2], j3 = srcs[p + 3];
        acc += x[j0] + x[j1] + x[j2] + x[j3];
    }
    for (; p < e; ++p) acc += x[srcs[p]];
    aggs[i] = acc;
}

__global__ __launch_bounds__(256)
void gather64(const float* __restrict__ h, const int* __restrict__ rowptr,
              const int* __restrict__ srcs, float* __restrict__ out, int n) {
    int node = blockIdx.x * 4 + (threadIdx.x >> 6);
    int lane = threadIdx.x & 63;
    if (node >= n) return;
    float acc = h[node * HD + lane];
    int s = rowptr[node], e = rowptr[node + 1];
    int p = s;
    for (; p + 4 <= e; p += 4) {
        int j0 = srcs[p], j1 = srcs[p + 1], j2 = srcs[p + 2], j3 = srcs[p + 3];
        float a0 = h[j0 * HD + lane];
        float a1 = h[j1 * HD + lane];
        float a2 = h[j2 * HD + lane];
        float a3 = h[j3 * HD + lane];
        acc += a0 + a1 + a2 + a3;
    }
    for (; p < e; ++p) acc += h[srcs[p] * HD + lane];
    out[node * HD + lane] = acc;
}

// ---------------- layer-0 expansion ----------------

__global__ __launch_bounds__(256)
void k_l0(const float* __restrict__ aggs, const float* __restrict__ w1,
          const float* __restrict__ b1, float* __restrict__ out, int total) {
    int idx = blockIdx.x * 256 + threadIdx.x;
    if (idx >= total) return;
    int i = idx >> 6, j = idx & 63;
    float v = aggs[i] * w1[j] + b1[j];
    out[idx] = fmaxf(v, 0.f);
}

// ---------------- fused 64x64 matmul + epilogue ----------------
// out[r][c] = epi( act( X[r,:]@W[:,c] + bias[c] ) )
// epi: (bn1) -> (+res) -> (*mask) -> (bn2)

template <int ACT>  // 0 = relu, 1 = leaky(0.01)
__global__ __launch_bounds__(256)
void mm64(const float* __restrict__ X, const float* __restrict__ W,
          const float* __restrict__ bias, const float* __restrict__ bn1,
          const float* __restrict__ res, const float* __restrict__ mask,
          const float* __restrict__ bn2, float* __restrict__ out, int n) {
    __shared__ float xt[HD * HD];
    int tid = threadIdx.x;
    int lane = tid & 63;
    int w = tid >> 6;
    int row0 = blockIdx.x * HD;

    float wv[HD];
#pragma unroll
    for (int k = 0; k < HD; ++k) wv[k] = W[k * HD + lane];
    float bv = bias[lane];
    float a1 = 1.f, c1 = 0.f, a2 = 1.f, c2 = 0.f;
    if (bn1) {
        float g = bn1[lane], be = bn1[64 + lane], mn = bn1[128 + lane], var = bn1[192 + lane];
        a1 = g / sqrtf(var + BN_EPS); c1 = be - mn * a1;
    }
    if (bn2) {
        float g = bn2[lane], be = bn2[64 + lane], mn = bn2[128 + lane], var = bn2[192 + lane];
        a2 = g / sqrtf(var + BN_EPS); c2 = be - mn * a2;
    }

    int maxf4 = n * 16;  // float4s in X
#pragma unroll
    for (int t = 0; t < 4; ++t) {
        int idx = tid + t * 256;
        int g4 = row0 * 16 + idx;
        float4 v = (g4 < maxf4) ? ((const float4*)X)[g4] : make_float4(0.f, 0.f, 0.f, 0.f);
        ((float4*)xt)[idx] = v;
    }
    __syncthreads();

#pragma unroll 1
    for (int rr = 0; rr < 16; ++rr) {
        int r = w * 16 + rr;
        int grow = row0 + r;
        float acc = 0.f;
#pragma unroll
        for (int k = 0; k < HD; k += 4) {
            float4 xv = *(const float4*)&xt[r * HD + k];
            acc += xv.x * wv[k] + xv.y * wv[k + 1] + xv.z * wv[k + 2] + xv.w * wv[k + 3];
        }
        float v = acc + bv;
        v = (ACT == 0) ? fmaxf(v, 0.f) : (v > 0.f ? v : 0.01f * v);
        if (bn1) v = v * a1 + c1;
        int gi = grow * HD + lane;
        if (grow < n) {
            if (res)  v += res[gi];
            if (mask) v *= mask[grow];
            if (bn2)  v = v * a2 + c2;
            out[gi] = v;
        }
    }
}

// ---------------- lin2 (H -> 1) ----------------

__global__ __launch_bounds__(256)
void k_lin2(const float* __restrict__ X, const float* __restrict__ w,
            const float* __restrict__ b, const float* __restrict__ mask,
            float* __restrict__ hs, int n) {
    int gt = blockIdx.x * 256 + threadIdx.x;
    int i = gt >> 6;
    int lane = gt & 63;
    if (i >= n) return;
    float v = X[i * HD + lane] * w[lane];
#pragma unroll
    for (int o = 32; o > 0; o >>= 1) v += __shfl_down(v, o, 64);
    if (lane == 0) {
        float z = v + b[0];
        z = z > 0.f ? z : 0.01f * z;
        hs[i] = z * mask[i];
    }
}

// ---------------- per-graph stats ----------------

__global__ __launch_bounds__(256)
void graph_stats(const float* __restrict__ hs, const float* __restrict__ deg,
                 const int* __restrict__ gstart, const float* __restrict__ recf,
                 const float* __restrict__ totv, const float* __restrict__ trand,
                 float* __restrict__ gmax, float* __restrict__ gmin,
                 float* __restrict__ gtar) {
    __shared__ float smx[256], smn[256], ssm[256];
    int b = blockIdx.x, tid = threadIdx.x;
    int s = gstart[b], e = gstart[b + 1];
    float mx = -INFINITY, mn = INFINITY, sm = 0.f;
    for (int i = s + tid; i < e; i += 256) {
        float v = hs[i];
        mx = fmaxf(mx, v); mn = fminf(mn, v); sm += deg[i];
    }
    smx[tid] = mx; smn[tid] = mn; ssm[tid] = sm;
    __syncthreads();
    for (int o = 128; o > 0; o >>= 1) {
        if (tid < o) {
            smx[tid] = fmaxf(smx[tid], smx[tid + o]);
            smn[tid] = fminf(smn[tid], smn[tid + o]);
            ssm[tid] += ssm[tid + o];
        }
        __syncthreads();
    }
    if (tid == 0) {
        gmax[b] = smx[0];
        gmin[b] = smn[0];
        float tv = ssm[0] + 1e-6f;
        float feas = recf[b] / totv[b];
        gtar[b] = (trand[b] * feas * 0.85f + 0.1f) * tv;
    }
}

__global__ __launch_bounds__(256)
void k_norm(float* __restrict__ hs, const float* __restrict__ mask,
            const float* __restrict__ x, const int* __restrict__ batch,
            const float* __restrict__ gmax, const float* __restrict__ gmin, int n) {
    int i = blockIdx.x * 256 + threadIdx.x;
    if (i >= n) return;
    int b = batch[i];
    float mn = gmin[b], mx = gmax[b];
    float v = (hs[i] - mn) / ((mx + 1e-6f) - mn);
    float m = mask[i];
    hs[i] = v * m + m * 1e-6f + x[i];
}

// ---------------- 30-iteration scan, one block per graph ----------------

__global__ __launch_bounds__(256)
void scan_iters(const float* __restrict__ hs, const float* __restrict__ deg,
                const float* __restrict__ mask, const int* __restrict__ gstart,
                const float* __restrict__ gtar, float* __restrict__ ga) {
    __shared__ float s1[256], s2[256];
    __shared__ float a_sh;
    int b = blockIdx.x, tid = threadIdx.x;
    int s = gstart[b], e = gstart[b + 1];
    float target = gtar[b];
    float a = 1.f;
    for (int it = 0; it < 30; ++it) {
        float dnk = 0.f, dot = 0.f;
        for (int i = s + tid; i < e; i += 256) {
            float hv = hs[i], d = deg[i], m = mask[i];
            float keep = (a * hv < 1.f) ? 1.f : 0.f;
            float km = keep * m;
            dnk += d * (m - km);
            dot += hv * d * km;
        }
        s1[tid] = dnk; s2[tid] = dot;
        __syncthreads();
        for (int o = 128; o > 0; o >>= 1) {
            if (tid < o) { s1[tid] += s1[tid + o]; s2[tid] += s2[tid + o]; }
            __syncthreads();
        }
        if (tid == 0) a_sh = (target - s1[0]) / (s2[0] + 1e-5f);
        __syncthreads();
        a = a_sh;
    }
    if (tid == 0) ga[b] = a;
}

// ---------------- probs + cut ----------------

__global__ __launch_bounds__(256)
void k_probs(const float* __restrict__ hs, const float* __restrict__ mask,
             const float* __restrict__ deg, const int* __restrict__ batch,
             const float* __restrict__ ga, float* __restrict__ out,
             float* __restrict__ cutpad, int n) {
    int i = blockIdx.x * 256 + threadIdx.x;
    bool valid = i < n;
    int b = valid ? batch[i] : 0;
    float contrib = 0.f;
    if (valid) {
        float p = ga[b] * hs[i] * mask[i];
        p = fminf(fmaxf(p, 0.f), 1.f);
        out[i] = p;
        contrib = p * deg[i];
    }
    int b0 = __shfl(b, 0, 64);
    bool uni = __all(b == b0);
    if (uni) {
#pragma unroll
        for (int o = 32; o > 0; o >>= 1) contrib += __shfl_down(contrib, o, 64);
        if ((threadIdx.x & 63) == 0) atomicAdd(&cutpad[b0 * 16], contrib);
    } else if (valid) {
        atomicAdd(&cutpad[b * 16], contrib);
    }
}

__global__ __launch_bounds__(256)
void cut_edges(const int* __restrict__ row, const int* __restrict__ col,
               const int* __restrict__ batch, const float* __restrict__ probs,
               float* __restrict__ cutpad, int E) {
    __shared__ float lc[128];
    int tid = threadIdx.x;
    if (tid < 128) lc[tid] = 0.f;
    __syncthreads();
    for (int e = blockIdx.x * 256 + tid; e < E; e += gridDim.x * 256) {
        int r = row[e], c = col[e];
        float v = probs[r] * probs[c];
        atomicAdd(&lc[batch[r]], v);
    }
    __syncthreads();
    if (tid < 128) {
        float v = lc[tid];
        if (v != 0.f) atomicAdd(&cutpad[tid * 16], -v);
    }
}

__global__ void k_loss(const float* __restrict__ cutpad, float* __restrict__ out, int nidx, int B) {
    __shared__ float sd[128];
    int tid = threadIdx.x;
    sd[tid] = (tid < B) ? cutpad[tid * 16] : 0.f;
    __syncthreads();
    for (int o = 64; o > 0; o >>= 1) {
        if (tid < o) sd[tid] += sd[tid + o];
        __syncthreads();
    }
    if (tid == 0) out[nidx] = sd[0] / (float)B;
}

// ---------------- host ----------------

extern "C" void kernel_launch(void* const* d_in, const int* in_sizes, int n_in,
                              void* d_out, int out_size, void* d_ws, size_t ws_size,
                              hipStream_t stream) {
    const float* x     = (const float*)d_in[0];
    const int*   ei    = (const int*)d_in[1];
    const int*   batch = (const int*)d_in[2];
    const float* recf  = (const float*)d_in[3];
    const float* totv  = (const float*)d_in[4];
    const float* trand = (const float*)d_in[5];
    const float* c1w1  = (const float*)d_in[6];
    const float* c1b1  = (const float*)d_in[7];
    const float* c1w2  = (const float*)d_in[8];
    const float* c1b2  = (const float*)d_in[9];
    const float* c1bn  = (const float*)d_in[10];
    const float* cw1   = (const float*)d_in[11];
    const float* cb1   = (const float*)d_in[12];
    const float* cw2   = (const float*)d_in[13];
    const float* cb2   = (const float*)d_in[14];
    const float* cbn   = (const float*)d_in[15];
    const float* obn   = (const float*)d_in[16];
    const float* l1w   = (const float*)d_in[17];
    const float* l1b   = (const float*)d_in[18];
    const float* bn2   = (const float*)d_in[19];
    const float* l2w   = (const float*)d_in[20];
    const float* l2b   = (const float*)d_in[21];

    int N  = in_sizes[0];
    int E  = in_sizes[1] / 2;
    int B  = in_sizes[3];
    int NL = in_sizes[11] / (HD * HD);
    const int* row = ei;
    const int* col = ei + E;

    long NH = (long)N * HD;
    float* ws    = (float*)d_ws;
    float* h     = ws;
    float* buf1  = h + NH;
    float* buf2  = buf1 + NH;
    float* maskA = buf2 + NH;
    float* maskB = maskA + N;
    float* deg   = maskB + N;
    float* hs    = deg + N;
    float* cutpad = hs + N;        // 2048 floats (B*16 padded)
    float* gmax  = cutpad + 2048;
    float* gmin  = gmax + B;
    float* gtar  = gmin + B;
    float* ga    = gtar + B;
    uintptr_t ip = (uintptr_t)(ga + B);
    ip = (ip + 15) & ~(uintptr_t)15;
    int* cnt    = (int*)ip;
    int* rowptr = cnt + N;
    int* bsum   = rowptr + N + 1;
    int* gstart = bsum + 1024;
    int* srcs   = gstart + (B + 2);

    dim3 blk(256);
    int gN  = (N + 255) / 256;
    int gE  = (E + 255) / 256;
    int nbS = (N + 1023) / 1024;
    int gMM = (N + 63) / 64;
    int g4  = (N + 3) / 4;

    // ---- preprocessing: masks, degrees, CSR ----
    k_init<<<gN, blk, 0, stream>>>(cnt, deg, cutpad, gstart, N, B);
    k_node_pre<<<gN, blk, 0, stream>>>(x, batch, maskA, gstart, N);
    k_count<<<gE, blk, 0, stream>>>(row, col, x, cnt, deg, maskA, E);
    scan_pass1<<<nbS, blk, 0, stream>>>(cnt, bsum, N);
    scan_pass2<<<1, 1, 0, stream>>>(bsum, nbS, rowptr, N, gstart, B);
    scan_pass3<<<nbS, blk, 0, stream>>>(cnt, bsum, rowptr, N);
    csr_fill<<<gE, blk, 0, stream>>>(row, col, rowptr, cnt, srcs, E);

    // ---- layer 0 (scalar input) ----
    k_gather_s<<<gN, blk, 0, stream>>>(x, rowptr, srcs, hs, N);
    k_l0<<<(int)((NH + 255) / 256), blk, 0, stream>>>(hs, c1w1, c1b1, buf2, (int)NH);
    mm64<0><<<gMM, blk, 0, stream>>>(buf2, c1w2, c1b2, c1bn, nullptr, maskA, nullptr, h, N);

    // ---- GIN loop ----
    for (int i = 0; i < NL; ++i) {
        gather64<<<g4, blk, 0, stream>>>(h, rowptr, srcs, buf1, N);
        mm64<0><<<gMM, blk, 0, stream>>>(buf1, cw1 + i * 4096, cb1 + i * 64,
                                         nullptr, nullptr, nullptr, nullptr, buf2, N);
        k_mask_init<<<gN, blk, 0, stream>>>(maskA, maskB, N);
        k_mask_or<<<gE, blk, 0, stream>>>(row, col, maskA, maskB, E);
        mm64<0><<<gMM, blk, 0, stream>>>(buf2, cw2 + i * 4096, cb2 + i * 64,
                                         cbn + i * 256, h, maskB, obn + i * 256, h, N);
        float* t = maskA; maskA = maskB; maskB = t;
    }

    // ---- head ----
    mm64<1><<<gMM, blk, 0, stream>>>(h, l1w, l1b, nullptr, nullptr, maskA, bn2, buf1, N);
    k_lin2<<<g4, blk, 0, stream>>>(buf1, l2w, l2b, maskA, hs, N);
    graph_stats<<<B, blk, 0, stream>>>(hs, deg, gstart, recf, totv, trand, gmax, gmin, gtar);
    k_norm<<<gN, blk, 0, stream>>>(hs, maskA, x, batch, gmax, gmin, N);
    scan_iters<<<B, blk, 0, stream>>>(hs, deg, maskA, gstart, gtar, ga);

    // ---- probs + cut loss ----
    k_probs<<<gN, blk, 0, stream>>>(hs, maskA, deg, batch, ga, (float*)d_out, cutpad, N);
    cut_edges<<<512, blk, 0, stream>>>(row, col, batch, (float*)d_out, cutpad, E);
    k_loss<<<1, 128, 0, stream>>>(cutpad, (float*)d_out, N, B);
}

// Round 2
// 1516.841 us; speedup vs baseline: 1.4373x; 1.4373x over previous
//
#include <hip/hip_runtime.h>
#include <stdint.h>

#define HD 64
#define BN_EPS 1e-5f
#define PCH 4096  // edges per partition block

// ---------------- init ----------------

__global__ __launch_bounds__(256)
void k_init(int* __restrict__ cnt, float* __restrict__ deg, float* __restrict__ cutpad,
            int* __restrict__ gstart, int* __restrict__ bucket_cnt, int n, int B) {
    int i = blockIdx.x * 256 + threadIdx.x;
    if (i < n) { cnt[i] = 0; deg[i] = 0.f; }
    if (i < 2048) cutpad[i] = 0.f;
    if (i <= B + 1) gstart[i] = n;  // sentinel
    if (i < 260) bucket_cnt[i] = 0;
}

// boundary detection (batch is sorted) — no atomics
__global__ __launch_bounds__(256)
void k_node_pre(const float* __restrict__ x, const int* __restrict__ batch,
                float* __restrict__ maskA, int* __restrict__ gstart, int n) {
    int i = blockIdx.x * 256 + threadIdx.x;
    if (i >= n) return;
    maskA[i] = (x[i] != 0.f) ? 1.f : 0.f;
    int b = batch[i];
    int bp = (i == 0) ? -1 : batch[i - 1];
    if (b != bp) gstart[b] = i;
}

// count in-degree (cnt), out-degree (deg), mask OR, bucket histogram
__global__ __launch_bounds__(256)
void k_count_hist(const int* __restrict__ row, const int* __restrict__ col,
                  const float* __restrict__ x, int* __restrict__ cnt,
                  float* __restrict__ deg, float* __restrict__ maskA,
                  int* __restrict__ bucket_cnt, int E, int shift) {
    __shared__ int hist[256];
    int tid = threadIdx.x;
    hist[tid] = 0;
    __syncthreads();
    int stride = gridDim.x * 256;
    for (int e = blockIdx.x * 256 + tid; e < E; e += stride) {
        int r = row[e], c = col[e];
        atomicAdd(&cnt[c], 1);
        atomicAdd(&deg[r], 1.0f);
        if (x[r] != 0.f) maskA[c] = 1.f;
        atomicAdd(&hist[c >> shift], 1);
    }
    __syncthreads();
    int h = hist[tid];
    if (h) atomicAdd(&bucket_cnt[tid], h);
}

// ---------------- prefix scans ----------------

__global__ __launch_bounds__(256)
void scan_pass1(const int* __restrict__ cnt, int* __restrict__ bsum, int n) {
    __shared__ int sd[256];
    int tid = threadIdx.x;
    int idx = blockIdx.x * 1024 + tid * 4;
    int4 v = make_int4(0, 0, 0, 0);
    if (idx + 3 < n) v = *(const int4*)(cnt + idx);
    else {
        if (idx     < n) v.x = cnt[idx];
        if (idx + 1 < n) v.y = cnt[idx + 1];
        if (idx + 2 < n) v.z = cnt[idx + 2];
        if (idx + 3 < n) v.w = cnt[idx + 3];
    }
    sd[tid] = v.x + v.y + v.z + v.w;
    __syncthreads();
    for (int o = 128; o > 0; o >>= 1) {
        if (tid < o) sd[tid] += sd[tid + o];
        __syncthreads();
    }
    if (tid == 0) bsum[blockIdx.x] = sd[0];
}

// one block: scan bsum (nb<=1024), scan buckets (NB<=256), gstart suffix-min
__global__ __launch_bounds__(256)
void scan_mid(int* __restrict__ bsum, int nb, int* __restrict__ rowptr, int n,
              int* __restrict__ gstart, int B,
              const int* __restrict__ bucket_cnt, int* __restrict__ bucket_cur, int NB) {
    __shared__ int sd[256];
    __shared__ int tot;
    int tid = threadIdx.x;
    // scan bsum, 4 elems/thread
    int base = tid * 4;
    int v[4];
#pragma unroll
    for (int k = 0; k < 4; ++k) v[k] = (base + k < nb) ? bsum[base + k] : 0;
    int s = v[0] + v[1] + v[2] + v[3];
    sd[tid] = s;
    __syncthreads();
    for (int o = 1; o < 256; o <<= 1) {
        int t = (tid >= o) ? sd[tid - o] : 0;
        __syncthreads();
        sd[tid] += t;
        __syncthreads();
    }
    int run = sd[tid] - s;
    if (tid == 255) tot = sd[255];
#pragma unroll
    for (int k = 0; k < 4; ++k) {
        if (base + k < nb) { int t = v[k]; bsum[base + k] = run; run += t; }
    }
    __syncthreads();
    if (tid == 0) rowptr[n] = tot;
    // bucket exclusive scan
    int bv = (tid < NB) ? bucket_cnt[tid] : 0;
    sd[tid] = bv;
    __syncthreads();
    for (int o = 1; o < 256; o <<= 1) {
        int t = (tid >= o) ? sd[tid - o] : 0;
        __syncthreads();
        sd[tid] += t;
        __syncthreads();
    }
    if (tid < NB) bucket_cur[tid] = sd[tid] - bv;
    __syncthreads();
    // gstart suffix min over [0..B]
    int g = (tid <= B) ? gstart[tid] : 0x7fffffff;
    sd[tid] = g;
    __syncthreads();
    for (int o = 1; o < 256; o <<= 1) {
        int t = (tid + o < 256) ? sd[tid + o] : 0x7fffffff;
        __syncthreads();
        sd[tid] = min(sd[tid], t);
        __syncthreads();
    }
    if (tid <= B) gstart[tid] = sd[tid];
}

__global__ __launch_bounds__(256)
void scan_pass3(int* __restrict__ cnt, const int* __restrict__ bsum,
                int* __restrict__ rowptr, int n) {
    __shared__ int sd[256];
    int tid = threadIdx.x;
    int idx = blockIdx.x * 1024 + tid * 4;
    int4 v = make_int4(0, 0, 0, 0);
    if (idx + 3 < n) v = *(const int4*)(cnt + idx);
    else {
        if (idx     < n) v.x = cnt[idx];
        if (idx + 1 < n) v.y = cnt[idx + 1];
        if (idx + 2 < n) v.z = cnt[idx + 2];
        if (idx + 3 < n) v.w = cnt[idx + 3];
    }
    int s = v.x + v.y + v.z + v.w;
    sd[tid] = s;
    __syncthreads();
    for (int o = 1; o < 256; o <<= 1) {
        int t = (tid >= o) ? sd[tid - o] : 0;
        __syncthreads();
        sd[tid] += t;
        __syncthreads();
    }
    int excl = sd[tid] - s + bsum[blockIdx.x];
    if (idx     < n) rowptr[idx]     = excl;
    if (idx + 1 < n) rowptr[idx + 1] = excl + v.x;
    if (idx + 2 < n) rowptr[idx + 2] = excl + v.x + v.y;
    if (idx + 3 < n) rowptr[idx + 3] = excl + v.x + v.y + v.z;
    if (idx + 3 < n) *(int4*)(cnt + idx) = make_int4(0, 0, 0, 0);
    else {
        if (idx     < n) cnt[idx]     = 0;
        if (idx + 1 < n) cnt[idx + 1] = 0;
        if (idx + 2 < n) cnt[idx + 2] = 0;
        if (idx + 3 < n) cnt[idx + 3] = 0;
    }
}

// ---------------- two-phase CSR fill ----------------

// partition edges into col-buckets (clustered writes, LDS ranking)
__global__ __launch_bounds__(256)
void k_partition(const int* __restrict__ row, const int* __restrict__ col,
                 int2* __restrict__ ebuf, int* __restrict__ bucket_cur,
                 int E, int shift) {
    __shared__ int hist[256];
    __shared__ int base[256];
    int tid = threadIdx.x;
    int e0 = blockIdx.x * PCH;
    hist[tid] = 0;
    __syncthreads();
    int myr[16], myc[16];
#pragma unroll
    for (int k = 0; k < 16; ++k) {
        int e = e0 + tid + k * 256;
        if (e < E) {
            myr[k] = row[e]; myc[k] = col[e];
            atomicAdd(&hist[myc[k] >> shift], 1);
        } else myc[k] = -1;
    }
    __syncthreads();
    int h = hist[tid];
    if (h) base[tid] = atomicAdd(&bucket_cur[tid], h);
    __syncthreads();
    hist[tid] = 0;
    __syncthreads();
#pragma unroll
    for (int k = 0; k < 16; ++k) {
        if (myc[k] >= 0) {
            int b = myc[k] >> shift;
            int pos = base[b] + atomicAdd(&hist[b], 1);
            ebuf[pos] = make_int2(myr[k], myc[k]);
        }
    }
}

// fill srcs from bucketed edges — cursor atomics & writes are L2-local.
// XCD-swizzled so each XCD owns a contiguous range of ebuf.
__global__ __launch_bounds__(256)
void k_fill(const int2* __restrict__ ebuf, const int* __restrict__ rowptr,
            int* __restrict__ cursor, int* __restrict__ srcs, int E) {
    int nb = gridDim.x;
    int q = nb >> 3, r = nb & 7;
    int orig = blockIdx.x;
    int xcd = orig & 7, idx = orig >> 3;
    int wg = (xcd < r ? xcd * (q + 1) : r * (q + 1) + (xcd - r) * q) + idx;
    int e = wg * 256 + threadIdx.x;
    if (e >= E) return;
    int2 rc = ebuf[e];
    int pos = rowptr[rc.y] + atomicAdd(&cursor[rc.y], 1);
    srcs[pos] = rc.x;
}

// ---------------- gathers ----------------

__global__ __launch_bounds__(256)
void k_gather_s(const float* __restrict__ x, const int* __restrict__ rowptr,
                const int* __restrict__ srcs, float* __restrict__ aggs, int n) {
    int i = blockIdx.x * 256 + threadIdx.x;
    if (i >= n) return;
    float acc = x[i];
    int s = rowptr[i], e = rowptr[i + 1];
    int p = s;
    for (; p + 4 <= e; p += 4) {
        int j0 = srcs[p], j1 = srcs[p + 1], j2 = srcs[p + 2], j3 = srcs[p + 3];
        acc += x[j0] + x[j1] + x[j2] + x[j3];
    }
    for (; p < e; ++p) acc += x[srcs[p]];
    aggs[i] = acc;
}

// h-gather + fused mask OR propagation (same CSR walk)
__global__ __launch_bounds__(256)
void gather64(const float* __restrict__ h, const int* __restrict__ rowptr,
              const int* __restrict__ srcs, const float* __restrict__ maskA,
              float* __restrict__ out, float* __restrict__ maskB, int n) {
    int node = blockIdx.x * 4 + (threadIdx.x >> 6);
    int lane = threadIdx.x & 63;
    if (node >= n) return;
    float acc = h[node * HD + lane];
    float m = maskA[node];
    int s = rowptr[node], e = rowptr[node + 1];
    int p = s;
    for (; p + 4 <= e; p += 4) {
        int j0 = srcs[p], j1 = srcs[p + 1], j2 = srcs[p + 2], j3 = srcs[p + 3];
        acc += h[j0 * HD + lane] + h[j1 * HD + lane]
             + h[j2 * HD + lane] + h[j3 * HD + lane];
        m += maskA[j0] + maskA[j1] + maskA[j2] + maskA[j3];
    }
    for (; p < e; ++p) { int j = srcs[p]; acc += h[j * HD + lane]; m += maskA[j]; }
    out[node * HD + lane] = acc;
    if (lane == 0) maskB[node] = (m > 0.f) ? 1.f : 0.f;
}

// ---------------- layer-0 expansion ----------------

__global__ __launch_bounds__(256)
void k_l0(const float* __restrict__ aggs, const float* __restrict__ w1,
          const float* __restrict__ b1, float* __restrict__ out, int total) {
    int idx = blockIdx.x * 256 + threadIdx.x;
    if (idx >= total) return;
    int i = idx >> 6, j = idx & 63;
    float v = aggs[i] * w1[j] + b1[j];
    out[idx] = fmaxf(v, 0.f);
}

// ---------------- fused 64x64 matmul + epilogue ----------------

template <int ACT>  // 0 = relu, 1 = leaky(0.01)
__global__ __launch_bounds__(256)
void mm64(const float* __restrict__ X, const float* __restrict__ W,
          const float* __restrict__ bias, const float* __restrict__ bn1,
          const float* __restrict__ res, const float* __restrict__ mask,
          const float* __restrict__ bn2, float* __restrict__ out, int n) {
    __shared__ float xt[HD * HD];
    int tid = threadIdx.x;
    int lane = tid & 63;
    int w = tid >> 6;
    int row0 = blockIdx.x * HD;

    float wv[HD];
#pragma unroll
    for (int k = 0; k < HD; ++k) wv[k] = W[k * HD + lane];
    float bv = bias[lane];
    float a1 = 1.f, c1 = 0.f, a2 = 1.f, c2 = 0.f;
    if (bn1) {
        float g = bn1[lane], be = bn1[64 + lane], mn = bn1[128 + lane], var = bn1[192 + lane];
        a1 = g / sqrtf(var + BN_EPS); c1 = be - mn * a1;
    }
    if (bn2) {
        float g = bn2[lane], be = bn2[64 + lane], mn = bn2[128 + lane], var = bn2[192 + lane];
        a2 = g / sqrtf(var + BN_EPS); c2 = be - mn * a2;
    }

    int maxf4 = n * 16;
#pragma unroll
    for (int t = 0; t < 4; ++t) {
        int idx = tid + t * 256;
        int g4 = row0 * 16 + idx;
        float4 v = (g4 < maxf4) ? ((const float4*)X)[g4] : make_float4(0.f, 0.f, 0.f, 0.f);
        ((float4*)xt)[idx] = v;
    }
    __syncthreads();

#pragma unroll 1
    for (int rr = 0; rr < 16; ++rr) {
        int r = w * 16 + rr;
        int grow = row0 + r;
        float acc = 0.f;
#pragma unroll
        for (int k = 0; k < HD; k += 4) {
            float4 xv = *(const float4*)&xt[r * HD + k];
            acc += xv.x * wv[k] + xv.y * wv[k + 1] + xv.z * wv[k + 2] + xv.w * wv[k + 3];
        }
        float v = acc + bv;
        v = (ACT == 0) ? fmaxf(v, 0.f) : (v > 0.f ? v : 0.01f * v);
        if (bn1) v = v * a1 + c1;
        int gi = grow * HD + lane;
        if (grow < n) {
            if (res)  v += res[gi];
            if (mask) v *= mask[grow];
            if (bn2)  v = v * a2 + c2;
            out[gi] = v;
        }
    }
}

// ---------------- lin2 (H -> 1) ----------------

__global__ __launch_bounds__(256)
void k_lin2(const float* __restrict__ X, const float* __restrict__ w,
            const float* __restrict__ b, const float* __restrict__ mask,
            float* __restrict__ hs, int n) {
    int gt = blockIdx.x * 256 + threadIdx.x;
    int i = gt >> 6;
    int lane = gt & 63;
    if (i >= n) return;
    float v = X[i * HD + lane] * w[lane];
#pragma unroll
    for (int o = 32; o > 0; o >>= 1) v += __shfl_down(v, o, 64);
    if (lane == 0) {
        float z = v + b[0];
        z = z > 0.f ? z : 0.01f * z;
        hs[i] = z * mask[i];
    }
}

// ---------------- per-graph stats ----------------

__global__ __launch_bounds__(256)
void graph_stats(const float* __restrict__ hs, const float* __restrict__ deg,
                 const int* __restrict__ gstart, const float* __restrict__ recf,
                 const float* __restrict__ totv, const float* __restrict__ trand,
                 float* __restrict__ gmax, float* __restrict__ gmin,
                 float* __restrict__ gtar) {
    __shared__ float smx[256], smn[256], ssm[256];
    int b = blockIdx.x, tid = threadIdx.x;
    int s = gstart[b], e = gstart[b + 1];
    float mx = -INFINITY, mn = INFINITY, sm = 0.f;
    for (int i = s + tid; i < e; i += 256) {
        float v = hs[i];
        mx = fmaxf(mx, v); mn = fminf(mn, v); sm += deg[i];
    }
    smx[tid] = mx; smn[tid] = mn; ssm[tid] = sm;
    __syncthreads();
    for (int o = 128; o > 0; o >>= 1) {
        if (tid < o) {
            smx[tid] = fmaxf(smx[tid], smx[tid + o]);
            smn[tid] = fminf(smn[tid], smn[tid + o]);
            ssm[tid] += ssm[tid + o];
        }
        __syncthreads();
    }
    if (tid == 0) {
        gmax[b] = smx[0];
        gmin[b] = smn[0];
        float tv = ssm[0] + 1e-6f;
        float feas = recf[b] / totv[b];
        gtar[b] = (trand[b] * feas * 0.85f + 0.1f) * tv;
    }
}

__global__ __launch_bounds__(256)
void k_norm(float* __restrict__ hs, const float* __restrict__ mask,
            const float* __restrict__ x, const int* __restrict__ batch,
            const float* __restrict__ gmax, const float* __restrict__ gmin, int n) {
    int i = blockIdx.x * 256 + threadIdx.x;
    if (i >= n) return;
    int b = batch[i];
    float mn = gmin[b], mx = gmax[b];
    float v = (hs[i] - mn) / ((mx + 1e-6f) - mn);
    float m = mask[i];
    hs[i] = v * m + m * 1e-6f + x[i];
}

// ---------------- 30-iteration scan, one block per graph ----------------
// Per-graph data cached in registers (<=2048 nodes/graph), 30 iters memory-free.

__global__ __launch_bounds__(256)
void scan_iters(const float* __restrict__ hs, const float* __restrict__ deg,
                const float* __restrict__ mask, const int* __restrict__ gstart,
                const float* __restrict__ gtar, float* __restrict__ ga) {
    __shared__ float w1[4], w2[4];
    __shared__ float a_sh;
    int b = blockIdx.x, tid = threadIdx.x;
    int lane = tid & 63, wid = tid >> 6;
    int s = gstart[b], e = gstart[b + 1];
    float target = gtar[b];
    int cnt = e - s;
    float a = 1.f;

    if (cnt <= 2048) {
        float hv[8], dm[8], hdm[8];
        float Sdm = 0.f;
#pragma unroll
        for (int k = 0; k < 8; ++k) {
            int i = s + tid + k * 256;
            float h_ = 0.f, d_ = 0.f, m_ = 0.f;
            if (i < e) { h_ = hs[i]; d_ = deg[i]; m_ = mask[i]; }
            hv[k] = h_;
            float t = d_ * m_;
            dm[k] = t;
            hdm[k] = h_ * t;
            Sdm += t;
        }
        // block-reduce Sdm once
        {
            float v = Sdm;
#pragma unroll
            for (int o = 32; o > 0; o >>= 1) v += __shfl_down(v, o, 64);
            if (lane == 0) w1[wid] = v;
            __syncthreads();
            if (tid == 0) a_sh = w1[0] + w1[1] + w1[2] + w1[3];
            __syncthreads();
            Sdm = a_sh;
            __syncthreads();
        }
        for (int it = 0; it < 30; ++it) {
            float t1 = 0.f, t2 = 0.f;
#pragma unroll
            for (int k = 0; k < 8; ++k) {
                float keep = (a * hv[k] < 1.f) ? 1.f : 0.f;
                t1 += dm[k] * keep;
                t2 += hdm[k] * keep;
            }
#pragma unroll
            for (int o = 32; o > 0; o >>= 1) {
                t1 += __shfl_down(t1, o, 64);
                t2 += __shfl_down(t2, o, 64);
            }
            if (lane == 0) { w1[wid] = t1; w2[wid] = t2; }
            __syncthreads();
            if (tid == 0) {
                float dnk = Sdm - (w1[0] + w1[1] + w1[2] + w1[3]);
                float dot = w2[0] + w2[1] + w2[2] + w2[3];
                a_sh = (target - dnk) / (dot + 1e-5f);
            }
            __syncthreads();
            a = a_sh;
        }
    } else {
        __shared__ float s1[256], s2[256];
        for (int it = 0; it < 30; ++it) {
            float dnk = 0.f, dot = 0.f;
            for (int i = s + tid; i < e; i += 256) {
                float hv = hs[i], d = deg[i], m = mask[i];
                float keep = (a * hv < 1.f) ? 1.f : 0.f;
                float km = keep * m;
                dnk += d * (m - km);
                dot += hv * d * km;
            }
            s1[tid] = dnk; s2[tid] = dot;
            __syncthreads();
            for (int o = 128; o > 0; o >>= 1) {
                if (tid < o) { s1[tid] += s1[tid + o]; s2[tid] += s2[tid + o]; }
                __syncthreads();
            }
            if (tid == 0) a_sh = (target - s1[0]) / (s2[0] + 1e-5f);
            __syncthreads();
            a = a_sh;
        }
    }
    if (tid == 0) ga[b] = a;
}

// ---------------- probs + cut ----------------

__global__ __launch_bounds__(256)
void k_probs(const float* __restrict__ hs, const float* __restrict__ mask,
             const float* __restrict__ deg, const int* __restrict__ batch,
             const float* __restrict__ ga, float* __restrict__ out,
             float* __restrict__ cutpad, int n) {
    int i = blockIdx.x * 256 + threadIdx.x;
    bool valid = i < n;
    int b = valid ? batch[i] : 0;
    float contrib = 0.f;
    if (valid) {
        float p = ga[b] * hs[i] * mask[i];
        p = fminf(fmaxf(p, 0.f), 1.f);
        out[i] = p;
        contrib = p * deg[i];
    }
    int b0 = __shfl(b, 0, 64);
    bool uni = __all(b == b0);
    if (uni) {
#pragma unroll
        for (int o = 32; o > 0; o >>= 1) contrib += __shfl_down(contrib, o, 64);
        if ((threadIdx.x & 63) == 0) atomicAdd(&cutpad[b0 * 16], contrib);
    } else if (valid) {
        atomicAdd(&cutpad[b * 16], contrib);
    }
}

__global__ __launch_bounds__(256)
void cut_edges(const int* __restrict__ row, const int* __restrict__ col,
               const int* __restrict__ batch, const float* __restrict__ probs,
               float* __restrict__ cutpad, int E) {
    __shared__ float lc[128];
    int tid = threadIdx.x;
    if (tid < 128) lc[tid] = 0.f;
    __syncthreads();
    for (int e = blockIdx.x * 256 + tid; e < E; e += gridDim.x * 256) {
        int r = row[e], c = col[e];
        float v = probs[r] * probs[c];
        atomicAdd(&lc[batch[r]], v);
    }
    __syncthreads();
    if (tid < 128) {
        float v = lc[tid];
        if (v != 0.f) atomicAdd(&cutpad[tid * 16], -v);
    }
}

__global__ void k_loss(const float* __restrict__ cutpad, float* __restrict__ out, int nidx, int B) {
    __shared__ float sd[128];
    int tid = threadIdx.x;
    sd[tid] = (tid < B) ? cutpad[tid * 16] : 0.f;
    __syncthreads();
    for (int o = 64; o > 0; o >>= 1) {
        if (tid < o) sd[tid] += sd[tid + o];
        __syncthreads();
    }
    if (tid == 0) out[nidx] = sd[0] / (float)B;
}

// ---------------- host ----------------

extern "C" void kernel_launch(void* const* d_in, const int* in_sizes, int n_in,
                              void* d_out, int out_size, void* d_ws, size_t ws_size,
                              hipStream_t stream) {
    const float* x     = (const float*)d_in[0];
    const int*   ei    = (const int*)d_in[1];
    const int*   batch = (const int*)d_in[2];
    const float* recf  = (const float*)d_in[3];
    const float* totv  = (const float*)d_in[4];
    const float* trand = (const float*)d_in[5];
    const float* c1w1  = (const float*)d_in[6];
    const float* c1b1  = (const float*)d_in[7];
    const float* c1w2  = (const float*)d_in[8];
    const float* c1b2  = (const float*)d_in[9];
    const float* c1bn  = (const float*)d_in[10];
    const float* cw1   = (const float*)d_in[11];
    const float* cb1   = (const float*)d_in[12];
    const float* cw2   = (const float*)d_in[13];
    const float* cb2   = (const float*)d_in[14];
    const float* cbn   = (const float*)d_in[15];
    const float* obn   = (const float*)d_in[16];
    const float* l1w   = (const float*)d_in[17];
    const float* l1b   = (const float*)d_in[18];
    const float* bn2   = (const float*)d_in[19];
    const float* l2w   = (const float*)d_in[20];
    const float* l2b   = (const float*)d_in[21];

    int N  = in_sizes[0];
    int E  = in_sizes[1] / 2;
    int B  = in_sizes[3];
    int NL = in_sizes[11] / (HD * HD);
    const int* row = ei;
    const int* col = ei + E;

    // bucket shift: NB <= 256
    int shift = 11;
    while ((((N - 1) >> shift) + 1) > 256) ++shift;
    int NB = ((N - 1) >> shift) + 1;

    long NH = (long)N * HD;
    float* ws    = (float*)d_ws;
    float* h     = ws;
    float* buf1  = h + NH;
    float* buf2  = buf1 + NH;
    float* maskA = buf2 + NH;
    float* maskB = maskA + N;
    float* deg   = maskB + N;
    float* hs    = deg + N;
    float* cutpad = hs + N;
    float* gmax  = cutpad + 2048;
    float* gmin  = gmax + B;
    float* gtar  = gmin + B;
    float* ga    = gtar + B;
    uintptr_t ip = (uintptr_t)(ga + B);
    ip = (ip + 15) & ~(uintptr_t)15;
    int* cnt        = (int*)ip;
    int* rowptr     = cnt + N;
    int* bsum       = rowptr + N + 1;
    int* gstart     = bsum + 1024;
    int* bucket_cnt = gstart + (B + 2);
    int* bucket_cur = bucket_cnt + 260;
    int* srcs       = bucket_cur + 260;
    int2* ebuf      = (int2*)buf2;   // alias: free until k_l0

    dim3 blk(256);
    int gN  = (N + 255) / 256;
    int gMM = (N + 63) / 64;
    int g4  = (N + 3) / 4;
    int nbS = (N + 1023) / 1024;
    int gP  = (E + PCH - 1) / PCH;
    int gF  = (E + 255) / 256;
    int gCH = min((E + 255) / 256, 1024);

    // ---- preprocessing ----
    k_init<<<gN, blk, 0, stream>>>(cnt, deg, cutpad, gstart, bucket_cnt, N, B);
    k_node_pre<<<gN, blk, 0, stream>>>(x, batch, maskA, gstart, N);
    k_count_hist<<<gCH, blk, 0, stream>>>(row, col, x, cnt, deg, maskA, bucket_cnt, E, shift);
    scan_pass1<<<nbS, blk, 0, stream>>>(cnt, bsum, N);
    scan_mid<<<1, blk, 0, stream>>>(bsum, nbS, rowptr, N, gstart, B, bucket_cnt, bucket_cur, NB);
    scan_pass3<<<nbS, blk, 0, stream>>>(cnt, bsum, rowptr, N);
    k_partition<<<gP, blk, 0, stream>>>(row, col, ebuf, bucket_cur, E, shift);
    k_fill<<<gF, blk, 0, stream>>>(ebuf, rowptr, cnt, srcs, E);

    // ---- layer 0 ----
    k_gather_s<<<gN, blk, 0, stream>>>(x, rowptr, srcs, hs, N);
    k_l0<<<(int)((NH + 255) / 256), blk, 0, stream>>>(hs, c1w1, c1b1, buf2, (int)NH);
    mm64<0><<<gMM, blk, 0, stream>>>(buf2, c1w2, c1b2, c1bn, nullptr, maskA, nullptr, h, N);

    // ---- GIN loop ----
    for (int i = 0; i < NL; ++i) {
        gather64<<<g4, blk, 0, stream>>>(h, rowptr, srcs, maskA, buf1, maskB, N);
        mm64<0><<<gMM, blk, 0, stream>>>(buf1, cw1 + i * 4096, cb1 + i * 64,
                                         nullptr, nullptr, nullptr, nullptr, buf2, N);
        mm64<0><<<gMM, blk, 0, stream>>>(buf2, cw2 + i * 4096, cb2 + i * 64,
                                         cbn + i * 256, h, maskB, obn + i * 256, h, N);
        float* t = maskA; maskA = maskB; maskB = t;
    }

    // ---- head ----
    mm64<1><<<gMM, blk, 0, stream>>>(h, l1w, l1b, nullptr, nullptr, maskA, bn2, buf1, N);
    k_lin2<<<g4, blk, 0, stream>>>(buf1, l2w, l2b, maskA, hs, N);
    graph_stats<<<B, blk, 0, stream>>>(hs, deg, gstart, recf, totv, trand, gmax, gmin, gtar);
    k_norm<<<gN, blk, 0, stream>>>(hs, maskA, x, batch, gmax, gmin, N);
    scan_iters<<<B, blk, 0, stream>>>(hs, deg, maskA, gstart, gtar, ga);

    // ---- probs + cut loss ----
    k_probs<<<gN, blk, 0, stream>>>(hs, maskA, deg, batch, ga, (float*)d_out, cutpad, N);
    cut_edges<<<512, blk, 0, stream>>>(row, col, batch, (float*)d_out, cutpad, E);
    k_loss<<<1, 128, 0, stream>>>(cutpad, (float*)d_out, N, B);
}

// Round 3
// 1228.367 us; speedup vs baseline: 1.7748x; 1.2348x over previous
//
#include <hip/hip_runtime.h>
#include <stdint.h>

#define HD 64
#define BN_EPS 1e-5f
#define PCH 4096        // edges per partition block
#define BSH 11          // bucket shift (2048 nodes/bucket)
#define BSZ 2048

// ---------------- init ----------------

__global__ __launch_bounds__(256)
void k_init(float* __restrict__ cutpad, int* __restrict__ gstart,
            int* __restrict__ bc_col, int* __restrict__ bc_row, int n, int B) {
    int i = blockIdx.x * 256 + threadIdx.x;
    if (i < 2048) cutpad[i] = 0.f;
    if (i <= B + 1) gstart[i] = n;  // sentinel
    if (i < 256) { bc_col[i] = 0; bc_row[i] = 0; }
}

// graph-start boundary detection (batch is sorted) — no atomics
__global__ __launch_bounds__(256)
void k_node_pre(const int* __restrict__ batch, int* __restrict__ gstart, int n) {
    int i = blockIdx.x * 256 + threadIdx.x;
    if (i >= n) return;
    int b = batch[i];
    int bp = (i == 0) ? -1 : batch[i - 1];
    if (b != bp) gstart[b] = i;
}

// bucket histograms (col and row), LDS-staged
__global__ __launch_bounds__(256)
void k_hist(const int* __restrict__ row, const int* __restrict__ col,
            int* __restrict__ bc_col, int* __restrict__ bc_row, int E) {
    __shared__ int hc[256], hr[256];
    int tid = threadIdx.x;
    hc[tid] = 0; hr[tid] = 0;
    __syncthreads();
    int stride = gridDim.x * 256;
    for (int e = blockIdx.x * 256 + tid; e < E; e += stride) {
        atomicAdd(&hc[col[e] >> BSH], 1);
        atomicAdd(&hr[row[e] >> BSH], 1);
    }
    __syncthreads();
    if (hc[tid]) atomicAdd(&bc_col[tid], hc[tid]);
    if (hr[tid]) atomicAdd(&bc_row[tid], hr[tid]);
}

// one block: bucket scans (col+row), gstart suffix-min, rowptr[n]
__global__ __launch_bounds__(256)
void scan_mid(const int* __restrict__ bc_col, const int* __restrict__ bc_row,
              int* __restrict__ cbase, int* __restrict__ rbase,
              int* __restrict__ cur_col, int* __restrict__ cur_row,
              int* __restrict__ gstart, int* __restrict__ rowptr,
              int n, int B, int NB, int E) {
    __shared__ int sd[256];
    int tid = threadIdx.x;
    // col buckets
    int v = (tid < NB) ? bc_col[tid] : 0;
    sd[tid] = v;
    __syncthreads();
    for (int o = 1; o < 256; o <<= 1) {
        int t = (tid >= o) ? sd[tid - o] : 0;
        __syncthreads(); sd[tid] += t; __syncthreads();
    }
    if (tid < NB) { int ex = sd[tid] - v; cbase[tid] = ex; cur_col[tid] = ex; }
    if (tid == 0) cbase[NB] = E;
    __syncthreads();
    // row buckets
    v = (tid < NB) ? bc_row[tid] : 0;
    sd[tid] = v;
    __syncthreads();
    for (int o = 1; o < 256; o <<= 1) {
        int t = (tid >= o) ? sd[tid - o] : 0;
        __syncthreads(); sd[tid] += t; __syncthreads();
    }
    if (tid < NB) { int ex = sd[tid] - v; rbase[tid] = ex; cur_row[tid] = ex; }
    if (tid == 0) rbase[NB] = E;
    __syncthreads();
    // gstart suffix-min over [0..B]
    int g = (tid <= B) ? gstart[tid] : 0x7fffffff;
    sd[tid] = g;
    __syncthreads();
    for (int o = 1; o < 256; o <<= 1) {
        int t = (tid + o < 256) ? sd[tid + o] : 0x7fffffff;
        __syncthreads(); sd[tid] = min(sd[tid], t); __syncthreads();
    }
    if (tid <= B) gstart[tid] = sd[tid];
    if (tid == 0) rowptr[n] = E;
}

// partition edges into col-buckets (int2) and row-buckets (int), clustered writes
__global__ __launch_bounds__(256)
void k_partition(const int* __restrict__ row, const int* __restrict__ col,
                 int2* __restrict__ ebuf, int* __restrict__ rbuf,
                 int* __restrict__ cur_col, int* __restrict__ cur_row, int E) {
    __shared__ int hc[256], hr[256], basec[256], baser[256];
    int tid = threadIdx.x;
    int e0 = blockIdx.x * PCH;
    hc[tid] = 0; hr[tid] = 0;
    __syncthreads();
    int myr[16], myc[16];
#pragma unroll
    for (int k = 0; k < 16; ++k) {
        int e = e0 + tid + k * 256;
        if (e < E) {
            myr[k] = row[e]; myc[k] = col[e];
            atomicAdd(&hc[myc[k] >> BSH], 1);
            atomicAdd(&hr[myr[k] >> BSH], 1);
        } else myc[k] = -1;
    }
    __syncthreads();
    if (hc[tid]) basec[tid] = atomicAdd(&cur_col[tid], hc[tid]);
    if (hr[tid]) baser[tid] = atomicAdd(&cur_row[tid], hr[tid]);
    __syncthreads();
    hc[tid] = 0; hr[tid] = 0;
    __syncthreads();
#pragma unroll
    for (int k = 0; k < 16; ++k) {
        if (myc[k] >= 0) {
            int bc = myc[k] >> BSH;
            int pos = basec[bc] + atomicAdd(&hc[bc], 1);
            ebuf[pos] = make_int2(myr[k], myc[k]);
            int br = myr[k] >> BSH;
            int pos2 = baser[br] + atomicAdd(&hr[br], 1);
            rbuf[pos2] = myr[k];
        }
    }
}

// per col-bucket: count in LDS, scan, write rowptr+maskA coalesced, fill srcs
// with LDS cursor atomics. Zero global atomics.
__global__ __launch_bounds__(256)
void k_bucket_csr(const int2* __restrict__ ebuf, const int* __restrict__ cbase,
                  const float* __restrict__ x, int* __restrict__ rowptr,
                  float* __restrict__ maskA, int* __restrict__ srcs, int n) {
    __shared__ int cnt2[BSZ];
    __shared__ int flg[BSZ];
    __shared__ int ss[256];
    int b = blockIdx.x, tid = threadIdx.x;
    int node0 = b << BSH;
    int e0 = cbase[b], e1 = cbase[b + 1];
#pragma unroll
    for (int k = 0; k < 8; ++k) { cnt2[tid + k * 256] = 0; flg[tid + k * 256] = 0; }
    __syncthreads();
    for (int e = e0 + tid; e < e1; e += 256) {
        int2 rc = ebuf[e];
        int lc = rc.y - node0;
        atomicAdd(&cnt2[lc], 1);
        if (x[rc.x] != 0.f) flg[lc] = 1;  // benign race
    }
    __syncthreads();
    // in-place exclusive scan of cnt2[2048]
    int base = tid * 8;
    int v[8];
#pragma unroll
    for (int k = 0; k < 8; ++k) v[k] = cnt2[base + k];
    int run = 0;
#pragma unroll
    for (int k = 0; k < 8; ++k) { int t = v[k]; v[k] = run; run += t; }
    ss[tid] = run;
    __syncthreads();
    for (int o = 1; o < 256; o <<= 1) {
        int t = (tid >= o) ? ss[tid - o] : 0;
        __syncthreads(); ss[tid] += t; __syncthreads();
    }
    int choff = ss[tid] - run;
#pragma unroll
    for (int k = 0; k < 8; ++k) cnt2[base + k] = v[k] + choff;
    __syncthreads();
    // coalesced rowptr + maskA writes
#pragma unroll
    for (int k = 0; k < 8; ++k) {
        int idx = tid + k * 256;
        int node = node0 + idx;
        if (node < n) {
            rowptr[node] = e0 + cnt2[idx];
            float own = (x[node] != 0.f) ? 1.f : 0.f;
            maskA[node] = (own != 0.f || flg[idx]) ? 1.f : 0.f;
        }
    }
    __syncthreads();
    // fill srcs via LDS cursors
    for (int e = e0 + tid; e < e1; e += 256) {
        int2 rc = ebuf[e];
        int lc = rc.y - node0;
        int pos = atomicAdd(&cnt2[lc], 1);
        srcs[e0 + pos] = rc.x;
    }
}

// per row-bucket: count out-degree in LDS, write deg coalesced
__global__ __launch_bounds__(256)
void k_bucket_deg(const int* __restrict__ rbuf, const int* __restrict__ rbase,
                  float* __restrict__ deg, int n) {
    __shared__ int cnt2[BSZ];
    int b = blockIdx.x, tid = threadIdx.x;
    int node0 = b << BSH;
    int e0 = rbase[b], e1 = rbase[b + 1];
#pragma unroll
    for (int k = 0; k < 8; ++k) cnt2[tid + k * 256] = 0;
    __syncthreads();
    for (int e = e0 + tid; e < e1; e += 256)
        atomicAdd(&cnt2[rbuf[e] - node0], 1);
    __syncthreads();
#pragma unroll
    for (int k = 0; k < 8; ++k) {
        int idx = tid + k * 256;
        int node = node0 + idx;
        if (node < n) deg[node] = (float)cnt2[idx];
    }
}

// ---------------- gathers ----------------

__global__ __launch_bounds__(256)
void k_gather_s(const float* __restrict__ x, const int* __restrict__ rowptr,
                const int* __restrict__ srcs, float* __restrict__ aggs, int n) {
    int i = blockIdx.x * 256 + threadIdx.x;
    if (i >= n) return;
    float acc = x[i];
    int s = rowptr[i], e = rowptr[i + 1];
    int p = s;
    for (; p + 4 <= e; p += 4) {
        int j0 = srcs[p], j1 = srcs[p + 1], j2 = srcs[p + 2], j3 = srcs[p + 3];
        acc += x[j0] + x[j1] + x[j2] + x[j3];
    }
    for (; p < e; ++p) acc += x[srcs[p]];
    aggs[i] = acc;
}

// h-gather + fused mask OR propagation (same CSR walk)
__global__ __launch_bounds__(256)
void gather64(const float* __restrict__ h, const int* __restrict__ rowptr,
              const int* __restrict__ srcs, const float* __restrict__ maskA,
              float* __restrict__ out, float* __restrict__ maskB, int n) {
    int node = blockIdx.x * 4 + (threadIdx.x >> 6);
    int lane = threadIdx.x & 63;
    if (node >= n) return;
    float acc = h[node * HD + lane];
    float m = maskA[node];
    int s = rowptr[node], e = rowptr[node + 1];
    int p = s;
    for (; p + 4 <= e; p += 4) {
        int j0 = srcs[p], j1 = srcs[p + 1], j2 = srcs[p + 2], j3 = srcs[p + 3];
        acc += h[j0 * HD + lane] + h[j1 * HD + lane]
             + h[j2 * HD + lane] + h[j3 * HD + lane];
        m += maskA[j0] + maskA[j1] + maskA[j2] + maskA[j3];
    }
    for (; p < e; ++p) { int j = srcs[p]; acc += h[j * HD + lane]; m += maskA[j]; }
    out[node * HD + lane] = acc;
    if (lane == 0) maskB[node] = (m > 0.f) ? 1.f : 0.f;
}

// ---------------- fused dense kernels ----------------

// layer 0: z1=relu(agg*w1+b1) built in LDS; out = bn1(relu(z1@W2+b2)) * mask
__global__ __launch_bounds__(256)
void mm64_l0(const float* __restrict__ agg, const float* __restrict__ w1,
             const float* __restrict__ b1, const float* __restrict__ W2,
             const float* __restrict__ b2, const float* __restrict__ bn1,
             const float* __restrict__ mask, float* __restrict__ out, int n) {
    __shared__ float xt2[HD * HD];
    int tid = threadIdx.x;
    int lane = tid & 63;
    int w = tid >> 6;
    int row0 = blockIdx.x * HD;

    float w1v = w1[lane], b1v = b1[lane];
#pragma unroll 4
    for (int rr = 0; rr < 16; ++rr) {
        int r = w * 16 + rr;
        int grow = row0 + r;
        float a = (grow < n) ? agg[grow] : 0.f;
        xt2[r * HD + lane] = fmaxf(a * w1v + b1v, 0.f);
    }
    float wv[HD];
#pragma unroll
    for (int k = 0; k < HD; ++k) wv[k] = W2[k * HD + lane];
    float bv = b2[lane];
    float g = bn1[lane], be = bn1[64 + lane], mn = bn1[128 + lane], var = bn1[192 + lane];
    float a1 = g / sqrtf(var + BN_EPS), c1 = be - mn * a1;
    __syncthreads();
#pragma unroll 1
    for (int rr = 0; rr < 16; ++rr) {
        int r = w * 16 + rr;
        int grow = row0 + r;
        float acc = 0.f;
#pragma unroll
        for (int k = 0; k < HD; k += 4) {
            float4 xv = *(const float4*)&xt2[r * HD + k];
            acc += xv.x * wv[k] + xv.y * wv[k + 1] + xv.z * wv[k + 2] + xv.w * wv[k + 3];
        }
        if (grow < n) {
            float v = fmaxf(acc + bv, 0.f) * a1 + c1;
            out[grow * HD + lane] = v * mask[grow];
        }
    }
}

// GIN layer: out = bn2( (res + bn1(relu(relu(X@W1+b1)@W2+b2))) * mask )
__global__ __launch_bounds__(256)
void mm64x2(const float* __restrict__ X, const float* __restrict__ W1,
            const float* __restrict__ b1, const float* __restrict__ W2,
            const float* __restrict__ b2, const float* __restrict__ bn1,
            const float* __restrict__ res, const float* __restrict__ mask,
            const float* __restrict__ bn2, float* __restrict__ out, int n) {
    __shared__ float xt[HD * HD];
    __shared__ float xt2[HD * HD];
    int tid = threadIdx.x;
    int lane = tid & 63;
    int w = tid >> 6;
    int row0 = blockIdx.x * HD;

    float wv[HD];
#pragma unroll
    for (int k = 0; k < HD; ++k) wv[k] = W1[k * HD + lane];
    float bv1 = b1[lane];

    int maxf4 = n * 16;
#pragma unroll
    for (int t = 0; t < 4; ++t) {
        int idx = tid + t * 256;
        int g4 = row0 * 16 + idx;
        float4 v = (g4 < maxf4) ? ((const float4*)X)[g4] : make_float4(0.f, 0.f, 0.f, 0.f);
        ((float4*)xt)[idx] = v;
    }
    __syncthreads();

#pragma unroll 1
    for (int rr = 0; rr < 16; ++rr) {
        int r = w * 16 + rr;
        float acc = 0.f;
#pragma unroll
        for (int k = 0; k < HD; k += 4) {
            float4 xv = *(const float4*)&xt[r * HD + k];
            acc += xv.x * wv[k] + xv.y * wv[k + 1] + xv.z * wv[k + 2] + xv.w * wv[k + 3];
        }
        xt2[r * HD + lane] = fmaxf(acc + bv1, 0.f);
    }

#pragma unroll
    for (int k = 0; k < HD; ++k) wv[k] = W2[k * HD + lane];
    float bv2 = b2[lane];
    float g = bn1[lane], be = bn1[64 + lane], mn = bn1[128 + lane], var = bn1[192 + lane];
    float a1 = g / sqrtf(var + BN_EPS), c1 = be - mn * a1;
    g = bn2[lane]; be = bn2[64 + lane]; mn = bn2[128 + lane]; var = bn2[192 + lane];
    float a2 = g / sqrtf(var + BN_EPS), c2 = be - mn * a2;
    __syncthreads();

#pragma unroll 1
    for (int rr = 0; rr < 16; ++rr) {
        int r = w * 16 + rr;
        int grow = row0 + r;
        float acc = 0.f;
#pragma unroll
        for (int k = 0; k < HD; k += 4) {
            float4 xv = *(const float4*)&xt2[r * HD + k];
            acc += xv.x * wv[k] + xv.y * wv[k + 1] + xv.z * wv[k + 2] + xv.w * wv[k + 3];
        }
        if (grow < n) {
            float v = fmaxf(acc + bv2, 0.f) * a1 + c1;
            int gi = grow * HD + lane;
            v = (v + res[gi]) * mask[grow];
            out[gi] = v * a2 + c2;
        }
    }
}

// head: t=leaky(X@l1w+b1)*mask; t=bn2(t); s=leaky(dot(t,l2w)+l2b)*mask -> hs
__global__ __launch_bounds__(256)
void mm64_head(const float* __restrict__ X, const float* __restrict__ W1,
               const float* __restrict__ b1, const float* __restrict__ mask,
               const float* __restrict__ bn2p, const float* __restrict__ l2w,
               const float* __restrict__ l2b, float* __restrict__ hs, int n) {
    __shared__ float xt[HD * HD];
    int tid = threadIdx.x;
    int lane = tid & 63;
    int w = tid >> 6;
    int row0 = blockIdx.x * HD;

    float wv[HD];
#pragma unroll
    for (int k = 0; k < HD; ++k) wv[k] = W1[k * HD + lane];
    float bv = b1[lane];
    float g = bn2p[lane], be = bn2p[64 + lane], mn = bn2p[128 + lane], var = bn2p[192 + lane];
    float a2 = g / sqrtf(var + BN_EPS), c2 = be - mn * a2;
    float w2v = l2w[lane];
    float b2v = l2b[0];

    int maxf4 = n * 16;
#pragma unroll
    for (int t = 0; t < 4; ++t) {
        int idx = tid + t * 256;
        int g4 = row0 * 16 + idx;
        float4 v = (g4 < maxf4) ? ((const float4*)X)[g4] : make_float4(0.f, 0.f, 0.f, 0.f);
        ((float4*)xt)[idx] = v;
    }
    __syncthreads();

#pragma unroll 1
    for (int rr = 0; rr < 16; ++rr) {
        int r = w * 16 + rr;
        int grow = row0 + r;
        float acc = 0.f;
#pragma unroll
        for (int k = 0; k < HD; k += 4) {
            float4 xv = *(const float4*)&xt[r * HD + k];
            acc += xv.x * wv[k] + xv.y * wv[k + 1] + xv.z * wv[k + 2] + xv.w * wv[k + 3];
        }
        float m = (grow < n) ? mask[grow] : 0.f;
        float v = acc + bv;
        v = (v > 0.f ? v : 0.01f * v) * m;
        v = v * a2 + c2;
        float contrib = v * w2v;
#pragma unroll
        for (int o = 32; o > 0; o >>= 1) contrib += __shfl_down(contrib, o, 64);
        if (lane == 0 && grow < n) {
            float z = contrib + b2v;
            z = z > 0.f ? z : 0.01f * z;
            hs[grow] = z * m;
        }
    }
}

// ---------------- per-graph stats ----------------

__global__ __launch_bounds__(256)
void graph_stats(const float* __restrict__ hs, const float* __restrict__ deg,
                 const int* __restrict__ gstart, const float* __restrict__ recf,
                 const float* __restrict__ totv, const float* __restrict__ trand,
                 float* __restrict__ gmax, float* __restrict__ gmin,
                 float* __restrict__ gtar) {
    __shared__ float smx[256], smn[256], ssm[256];
    int b = blockIdx.x, tid = threadIdx.x;
    int s = gstart[b], e = gstart[b + 1];
    float mx = -INFINITY, mn = INFINITY, sm = 0.f;
    for (int i = s + tid; i < e; i += 256) {
        float v = hs[i];
        mx = fmaxf(mx, v); mn = fminf(mn, v); sm += deg[i];
    }
    smx[tid] = mx; smn[tid] = mn; ssm[tid] = sm;
    __syncthreads();
    for (int o = 128; o > 0; o >>= 1) {
        if (tid < o) {
            smx[tid] = fmaxf(smx[tid], smx[tid + o]);
            smn[tid] = fminf(smn[tid], smn[tid + o]);
            ssm[tid] += ssm[tid + o];
        }
        __syncthreads();
    }
    if (tid == 0) {
        gmax[b] = smx[0];
        gmin[b] = smn[0];
        float tv = ssm[0] + 1e-6f;
        float feas = recf[b] / totv[b];
        gtar[b] = (trand[b] * feas * 0.85f + 0.1f) * tv;
    }
}

__global__ __launch_bounds__(256)
void k_norm(float* __restrict__ hs, const float* __restrict__ mask,
            const float* __restrict__ x, const int* __restrict__ batch,
            const float* __restrict__ gmax, const float* __restrict__ gmin, int n) {
    int i = blockIdx.x * 256 + threadIdx.x;
    if (i >= n) return;
    int b = batch[i];
    float mn = gmin[b], mx = gmax[b];
    float v = (hs[i] - mn) / ((mx + 1e-6f) - mn);
    float m = mask[i];
    hs[i] = v * m + m * 1e-6f + x[i];
}

// ---------------- 30-iteration scan ----------------

__global__ __launch_bounds__(256)
void scan_iters(const float* __restrict__ hs, const float* __restrict__ deg,
                const float* __restrict__ mask, const int* __restrict__ gstart,
                const float* __restrict__ gtar, float* __restrict__ ga) {
    __shared__ float w1[4], w2[4];
    __shared__ float a_sh;
    int b = blockIdx.x, tid = threadIdx.x;
    int lane = tid & 63, wid = tid >> 6;
    int s = gstart[b], e = gstart[b + 1];
    float target = gtar[b];
    int cnt = e - s;
    float a = 1.f;

    if (cnt <= 2048) {
        float hv[8], dm[8], hdm[8];
        float Sdm = 0.f;
#pragma unroll
        for (int k = 0; k < 8; ++k) {
            int i = s + tid + k * 256;
            float h_ = 0.f, d_ = 0.f, m_ = 0.f;
            if (i < e) { h_ = hs[i]; d_ = deg[i]; m_ = mask[i]; }
            hv[k] = h_;
            float t = d_ * m_;
            dm[k] = t;
            hdm[k] = h_ * t;
            Sdm += t;
        }
        {
            float v = Sdm;
#pragma unroll
            for (int o = 32; o > 0; o >>= 1) v += __shfl_down(v, o, 64);
            if (lane == 0) w1[wid] = v;
            __syncthreads();
            if (tid == 0) a_sh = w1[0] + w1[1] + w1[2] + w1[3];
            __syncthreads();
            Sdm = a_sh;
            __syncthreads();
        }
        for (int it = 0; it < 30; ++it) {
            float t1 = 0.f, t2 = 0.f;
#pragma unroll
            for (int k = 0; k < 8; ++k) {
                float keep = (a * hv[k] < 1.f) ? 1.f : 0.f;
                t1 += dm[k] * keep;
                t2 += hdm[k] * keep;
            }
#pragma unroll
            for (int o = 32; o > 0; o >>= 1) {
                t1 += __shfl_down(t1, o, 64);
                t2 += __shfl_down(t2, o, 64);
            }
            if (lane == 0) { w1[wid] = t1; w2[wid] = t2; }
            __syncthreads();
            if (tid == 0) {
                float dnk = Sdm - (w1[0] + w1[1] + w1[2] + w1[3]);
                float dot = w2[0] + w2[1] + w2[2] + w2[3];
                a_sh = (target - dnk) / (dot + 1e-5f);
            }
            __syncthreads();
            a = a_sh;
        }
    } else {
        __shared__ float s1[256], s2[256];
        for (int it = 0; it < 30; ++it) {
            float dnk = 0.f, dot = 0.f;
            for (int i = s + tid; i < e; i += 256) {
                float hv = hs[i], d = deg[i], m = mask[i];
                float keep = (a * hv < 1.f) ? 1.f : 0.f;
                float km = keep * m;
                dnk += d * (m - km);
                dot += hv * d * km;
            }
            s1[tid] = dnk; s2[tid] = dot;
            __syncthreads();
            for (int o = 128; o > 0; o >>= 1) {
                if (tid < o) { s1[tid] += s1[tid + o]; s2[tid] += s2[tid + o]; }
                __syncthreads();
            }
            if (tid == 0) a_sh = (target - s1[0]) / (s2[0] + 1e-5f);
            __syncthreads();
            a = a_sh;
        }
    }
    if (tid == 0) ga[b] = a;
}

// ---------------- probs + cut ----------------

__global__ __launch_bounds__(256)
void k_probs(const float* __restrict__ hs, const float* __restrict__ mask,
             const float* __restrict__ deg, const int* __restrict__ batch,
             const float* __restrict__ ga, float* __restrict__ out,
             float* __restrict__ cutpad, int n) {
    int i = blockIdx.x * 256 + threadIdx.x;
    bool valid = i < n;
    int b = valid ? batch[i] : 0;
    float contrib = 0.f;
    if (valid) {
        float p = ga[b] * hs[i] * mask[i];
        p = fminf(fmaxf(p, 0.f), 1.f);
        out[i] = p;
        contrib = p * deg[i];
    }
    int b0 = __shfl(b, 0, 64);
    bool uni = __all(b == b0);
    if (uni) {
#pragma unroll
        for (int o = 32; o > 0; o >>= 1) contrib += __shfl_down(contrib, o, 64);
        if ((threadIdx.x & 63) == 0) atomicAdd(&cutpad[b0 * 16], contrib);
    } else if (valid) {
        atomicAdd(&cutpad[b * 16], contrib);
    }
}

__global__ __launch_bounds__(256)
void cut_edges(const int* __restrict__ row, const int* __restrict__ col,
               const int* __restrict__ batch, const float* __restrict__ probs,
               float* __restrict__ cutpad, int E) {
    __shared__ float lc[128];
    int tid = threadIdx.x;
    if (tid < 128) lc[tid] = 0.f;
    __syncthreads();
    for (int e = blockIdx.x * 256 + tid; e < E; e += gridDim.x * 256) {
        int r = row[e], c = col[e];
        float v = probs[r] * probs[c];
        atomicAdd(&lc[batch[r]], v);
    }
    __syncthreads();
    if (tid < 128) {
        float v = lc[tid];
        if (v != 0.f) atomicAdd(&cutpad[tid * 16], -v);
    }
}

__global__ void k_loss(const float* __restrict__ cutpad, float* __restrict__ out, int nidx, int B) {
    __shared__ float sd[128];
    int tid = threadIdx.x;
    sd[tid] = (tid < B) ? cutpad[tid * 16] : 0.f;
    __syncthreads();
    for (int o = 64; o > 0; o >>= 1) {
        if (tid < o) sd[tid] += sd[tid + o];
        __syncthreads();
    }
    if (tid == 0) out[nidx] = sd[0] / (float)B;
}

// ---------------- host ----------------

extern "C" void kernel_launch(void* const* d_in, const int* in_sizes, int n_in,
                              void* d_out, int out_size, void* d_ws, size_t ws_size,
                              hipStream_t stream) {
    const float* x     = (const float*)d_in[0];
    const int*   ei    = (const int*)d_in[1];
    const int*   batch = (const int*)d_in[2];
    const float* recf  = (const float*)d_in[3];
    const float* totv  = (const float*)d_in[4];
    const float* trand = (const float*)d_in[5];
    const float* c1w1  = (const float*)d_in[6];
    const float* c1b1  = (const float*)d_in[7];
    const float* c1w2  = (const float*)d_in[8];
    const float* c1b2  = (const float*)d_in[9];
    const float* c1bn  = (const float*)d_in[10];
    const float* cw1   = (const float*)d_in[11];
    const float* cb1   = (const float*)d_in[12];
    const float* cw2   = (const float*)d_in[13];
    const float* cb2   = (const float*)d_in[14];
    const float* cbn   = (const float*)d_in[15];
    const float* obn   = (const float*)d_in[16];
    const float* l1w   = (const float*)d_in[17];
    const float* l1b   = (const float*)d_in[18];
    const float* bn2   = (const float*)d_in[19];
    const float* l2w   = (const float*)d_in[20];
    const float* l2b   = (const float*)d_in[21];

    int N  = in_sizes[0];
    int E  = in_sizes[1] / 2;
    int B  = in_sizes[3];
    int NL = in_sizes[11] / (HD * HD);
    const int* row = ei;
    const int* col = ei + E;
    int NB = (N + BSZ - 1) >> BSH;  // <=256 for N<=524288

    long NH = (long)N * HD;
    float* ws    = (float*)d_ws;
    float* h     = ws;
    float* buf1  = h + NH;
    float* buf2  = buf1 + NH;
    float* maskA = buf2 + NH;
    float* maskB = maskA + N;
    float* deg   = maskB + N;
    float* hs    = deg + N;
    float* cutpad = hs + N;
    float* gmax  = cutpad + 2048;
    float* gmin  = gmax + B;
    float* gtar  = gmin + B;
    float* ga    = gtar + B;
    uintptr_t ip = (uintptr_t)(ga + B);
    ip = (ip + 15) & ~(uintptr_t)15;
    int* rowptr  = (int*)ip;
    int* gstart  = rowptr + N + 1;
    int* bc_col  = gstart + (B + 2);
    int* bc_row  = bc_col + 256;
    int* cbase   = bc_row + 256;
    int* rbase   = cbase + 257;
    int* cur_col = rbase + 257;
    int* cur_row = cur_col + 256;
    int* srcs    = cur_row + 256;
    int2* ebuf   = (int2*)buf2;   // alias (free until mm64_l0 output path)
    int* rbuf    = (int*)buf1;    // alias (free until gather64 output)

    dim3 blk(256);
    int gN  = (N + 255) / 256;
    int gMM = (N + 63) / 64;
    int g4  = (N + 3) / 4;
    int gP  = (E + PCH - 1) / PCH;
    int gH  = min((E + 255) / 256, 1024);

    // ---- preprocessing ----
    k_init<<<gN, blk, 0, stream>>>(cutpad, gstart, bc_col, bc_row, N, B);
    k_node_pre<<<gN, blk, 0, stream>>>(batch, gstart, N);
    k_hist<<<gH, blk, 0, stream>>>(row, col, bc_col, bc_row, E);
    scan_mid<<<1, blk, 0, stream>>>(bc_col, bc_row, cbase, rbase, cur_col, cur_row,
                                    gstart, rowptr, N, B, NB, E);
    k_partition<<<gP, blk, 0, stream>>>(row, col, ebuf, rbuf, cur_col, cur_row, E);
    k_bucket_csr<<<NB, blk, 0, stream>>>(ebuf, cbase, x, rowptr, maskA, srcs, N);
    k_bucket_deg<<<NB, blk, 0, stream>>>(rbuf, rbase, deg, N);

    // ---- layer 0 ----
    k_gather_s<<<gN, blk, 0, stream>>>(x, rowptr, srcs, hs, N);
    mm64_l0<<<gMM, blk, 0, stream>>>(hs, c1w1, c1b1, c1w2, c1b2, c1bn, maskA, h, N);

    // ---- GIN loop ----
    for (int i = 0; i < NL; ++i) {
        gather64<<<g4, blk, 0, stream>>>(h, rowptr, srcs, maskA, buf1, maskB, N);
        mm64x2<<<gMM, blk, 0, stream>>>(buf1, cw1 + i * 4096, cb1 + i * 64,
                                        cw2 + i * 4096, cb2 + i * 64,
                                        cbn + i * 256, h, maskB, obn + i * 256, h, N);
        float* t = maskA; maskA = maskB; maskB = t;
    }

    // ---- head ----
    mm64_head<<<gMM, blk, 0, stream>>>(h, l1w, l1b, maskA, bn2, l2w, l2b, hs, N);
    graph_stats<<<B, blk, 0, stream>>>(hs, deg, gstart, recf, totv, trand, gmax, gmin, gtar);
    k_norm<<<gN, blk, 0, stream>>>(hs, maskA, x, batch, gmax, gmin, N);
    scan_iters<<<B, blk, 0, stream>>>(hs, deg, maskA, gstart, gtar, ga);

    // ---- probs + cut loss ----
    k_probs<<<gN, blk, 0, stream>>>(hs, maskA, deg, batch, ga, (float*)d_out, cutpad, N);
    cut_edges<<<512, blk, 0, stream>>>(row, col, batch, (float*)d_out, cutpad, E);
    k_loss<<<1, 128, 0, stream>>>(cutpad, (float*)d_out, N, B);
}

// Round 4
// 836.111 us; speedup vs baseline: 2.6075x; 1.4691x over previous
//
#include <hip/hip_runtime.h>
#include <stdint.h>

#define HD 64
#define BN_EPS 1e-5f
#define PCH 4096        // edges per partition block
#define BSH 11          // bucket shift (2048 nodes/bucket)
#define BSZ 2048

typedef __attribute__((ext_vector_type(8))) short s16x8;
typedef __attribute__((ext_vector_type(4))) float f32x4;

__device__ inline ushort f2bf(float f) {
    union { float f; uint u; } v; v.f = f;
    uint u = v.u + 0x7fffu + ((v.u >> 16) & 1u);
    return (ushort)(u >> 16);
}
__device__ inline float bf2f(ushort b) {
    union { uint u; float f; } v; v.u = ((uint)b) << 16; return v.f;
}

// ---------------- init ----------------

__global__ __launch_bounds__(256)
void k_init(float* __restrict__ cutpad, int* __restrict__ gstart,
            int* __restrict__ bc_col, int* __restrict__ bc_row, int n, int B) {
    int i = blockIdx.x * 256 + threadIdx.x;
    if (i < 2048) cutpad[i] = 0.f;
    if (i <= B + 1) gstart[i] = n;  // sentinel
    if (i < 256) { bc_col[i] = 0; bc_row[i] = 0; }
}

__global__ __launch_bounds__(256)
void k_node_pre(const int* __restrict__ batch, int* __restrict__ gstart, int n) {
    int i = blockIdx.x * 256 + threadIdx.x;
    if (i >= n) return;
    int b = batch[i];
    int bp = (i == 0) ? -1 : batch[i - 1];
    if (b != bp) gstart[b] = i;
}

// bucket histograms (col and row), LDS-staged
__global__ __launch_bounds__(256)
void k_hist(const int* __restrict__ row, const int* __restrict__ col,
            int* __restrict__ bc_col, int* __restrict__ bc_row, int E) {
    __shared__ int hc[256], hr[256];
    int tid = threadIdx.x;
    hc[tid] = 0; hr[tid] = 0;
    __syncthreads();
    int stride = gridDim.x * 256;
    for (int e = blockIdx.x * 256 + tid; e < E; e += stride) {
        atomicAdd(&hc[col[e] >> BSH], 1);
        atomicAdd(&hr[row[e] >> BSH], 1);
    }
    __syncthreads();
    if (hc[tid]) atomicAdd(&bc_col[tid], hc[tid]);
    if (hr[tid]) atomicAdd(&bc_row[tid], hr[tid]);
}

// one block: bucket scans (col+row), gstart suffix-min, rowptr[n]
__global__ __launch_bounds__(256)
void scan_mid(const int* __restrict__ bc_col, const int* __restrict__ bc_row,
              int* __restrict__ cbase, int* __restrict__ rbase,
              int* __restrict__ cur_col, int* __restrict__ cur_row,
              int* __restrict__ gstart, int* __restrict__ rowptr,
              int n, int B, int NB, int E) {
    __shared__ int sd[256];
    int tid = threadIdx.x;
    int v = (tid < NB) ? bc_col[tid] : 0;
    sd[tid] = v;
    __syncthreads();
    for (int o = 1; o < 256; o <<= 1) {
        int t = (tid >= o) ? sd[tid - o] : 0;
        __syncthreads(); sd[tid] += t; __syncthreads();
    }
    if (tid < NB) { int ex = sd[tid] - v; cbase[tid] = ex; cur_col[tid] = ex; }
    if (tid == 0) cbase[NB] = E;
    __syncthreads();
    v = (tid < NB) ? bc_row[tid] : 0;
    sd[tid] = v;
    __syncthreads();
    for (int o = 1; o < 256; o <<= 1) {
        int t = (tid >= o) ? sd[tid - o] : 0;
        __syncthreads(); sd[tid] += t; __syncthreads();
    }
    if (tid < NB) { int ex = sd[tid] - v; rbase[tid] = ex; cur_row[tid] = ex; }
    if (tid == 0) rbase[NB] = E;
    __syncthreads();
    int g = (tid <= B) ? gstart[tid] : 0x7fffffff;
    sd[tid] = g;
    __syncthreads();
    for (int o = 1; o < 256; o <<= 1) {
        int t = (tid + o < 256) ? sd[tid + o] : 0x7fffffff;
        __syncthreads(); sd[tid] = min(sd[tid], t); __syncthreads();
    }
    if (tid <= B) gstart[tid] = sd[tid];
    if (tid == 0) rowptr[n] = E;
}

// partition edges into col-buckets (int2) and row-buckets (int)
__global__ __launch_bounds__(256)
void k_partition(const int* __restrict__ row, const int* __restrict__ col,
                 int2* __restrict__ ebuf, int* __restrict__ rbuf,
                 int* __restrict__ cur_col, int* __restrict__ cur_row, int E) {
    __shared__ int hc[256], hr[256], basec[256], baser[256];
    int tid = threadIdx.x;
    int e0 = blockIdx.x * PCH;
    hc[tid] = 0; hr[tid] = 0;
    __syncthreads();
    int myr[16], myc[16];
#pragma unroll
    for (int k = 0; k < 16; ++k) {
        int e = e0 + tid + k * 256;
        if (e < E) {
            myr[k] = row[e]; myc[k] = col[e];
            atomicAdd(&hc[myc[k] >> BSH], 1);
            atomicAdd(&hr[myr[k] >> BSH], 1);
        } else myc[k] = -1;
    }
    __syncthreads();
    if (hc[tid]) basec[tid] = atomicAdd(&cur_col[tid], hc[tid]);
    if (hr[tid]) baser[tid] = atomicAdd(&cur_row[tid], hr[tid]);
    __syncthreads();
    hc[tid] = 0; hr[tid] = 0;
    __syncthreads();
#pragma unroll
    for (int k = 0; k < 16; ++k) {
        if (myc[k] >= 0) {
            int bc = myc[k] >> BSH;
            int pos = basec[bc] + atomicAdd(&hc[bc], 1);
            ebuf[pos] = make_int2(myr[k], myc[k]);
            int br = myr[k] >> BSH;
            int pos2 = baser[br] + atomicAdd(&hr[br], 1);
            rbuf[pos2] = myr[k];
        }
    }
}

// per col-bucket: LDS count + scan -> rowptr/maskA coalesced, srcs via LDS cursors
__global__ __launch_bounds__(256)
void k_bucket_csr(const int2* __restrict__ ebuf, const int* __restrict__ cbase,
                  const float* __restrict__ x, int* __restrict__ rowptr,
                  float* __restrict__ maskA, int* __restrict__ srcs, int n) {
    __shared__ int cnt2[BSZ];
    __shared__ int flg[BSZ];
    __shared__ int ss[256];
    int b = blockIdx.x, tid = threadIdx.x;
    int node0 = b << BSH;
    int e0 = cbase[b], e1 = cbase[b + 1];
#pragma unroll
    for (int k = 0; k < 8; ++k) { cnt2[tid + k * 256] = 0; flg[tid + k * 256] = 0; }
    __syncthreads();
    for (int e = e0 + tid; e < e1; e += 256) {
        int2 rc = ebuf[e];
        int lc = rc.y - node0;
        atomicAdd(&cnt2[lc], 1);
        if (x[rc.x] != 0.f) flg[lc] = 1;  // benign race
    }
    __syncthreads();
    int base = tid * 8;
    int v[8];
#pragma unroll
    for (int k = 0; k < 8; ++k) v[k] = cnt2[base + k];
    int run = 0;
#pragma unroll
    for (int k = 0; k < 8; ++k) { int t = v[k]; v[k] = run; run += t; }
    ss[tid] = run;
    __syncthreads();
    for (int o = 1; o < 256; o <<= 1) {
        int t = (tid >= o) ? ss[tid - o] : 0;
        __syncthreads(); ss[tid] += t; __syncthreads();
    }
    int choff = ss[tid] - run;
#pragma unroll
    for (int k = 0; k < 8; ++k) cnt2[base + k] = v[k] + choff;
    __syncthreads();
#pragma unroll
    for (int k = 0; k < 8; ++k) {
        int idx = tid + k * 256;
        int node = node0 + idx;
        if (node < n) {
            rowptr[node] = e0 + cnt2[idx];
            float own = (x[node] != 0.f) ? 1.f : 0.f;
            maskA[node] = (own != 0.f || flg[idx]) ? 1.f : 0.f;
        }
    }
    __syncthreads();
    for (int e = e0 + tid; e < e1; e += 256) {
        int2 rc = ebuf[e];
        int lc = rc.y - node0;
        int pos = atomicAdd(&cnt2[lc], 1);
        srcs[e0 + pos] = rc.x;
    }
}

// per row-bucket: out-degree in LDS, deg coalesced
__global__ __launch_bounds__(256)
void k_bucket_deg(const int* __restrict__ rbuf, const int* __restrict__ rbase,
                  float* __restrict__ deg, int n) {
    __shared__ int cnt2[BSZ];
    int b = blockIdx.x, tid = threadIdx.x;
    int node0 = b << BSH;
    int e0 = rbase[b], e1 = rbase[b + 1];
#pragma unroll
    for (int k = 0; k < 8; ++k) cnt2[tid + k * 256] = 0;
    __syncthreads();
    for (int e = e0 + tid; e < e1; e += 256)
        atomicAdd(&cnt2[rbuf[e] - node0], 1);
    __syncthreads();
#pragma unroll
    for (int k = 0; k < 8; ++k) {
        int idx = tid + k * 256;
        int node = node0 + idx;
        if (node < n) deg[node] = (float)cnt2[idx];
    }
}

// ---------------- gathers ----------------

__global__ __launch_bounds__(256)
void k_gather_s(const float* __restrict__ x, const int* __restrict__ rowptr,
                const int* __restrict__ srcs, float* __restrict__ aggs, int n) {
    int i = blockIdx.x * 256 + threadIdx.x;
    if (i >= n) return;
    float acc = x[i];
    int s = rowptr[i], e = rowptr[i + 1];
    int p = s;
    for (; p + 4 <= e; p += 4) {
        int j0 = srcs[p], j1 = srcs[p + 1], j2 = srcs[p + 2], j3 = srcs[p + 3];
        acc += x[j0] + x[j1] + x[j2] + x[j3];
    }
    for (; p < e; ++p) acc += x[srcs[p]];
    aggs[i] = acc;
}

// bf16 h-gather + fused mask OR propagation; srcs walk is wave-uniform (scalar loads)
__global__ __launch_bounds__(256)
void gather64b(const ushort* __restrict__ hb, const int* __restrict__ rowptr,
               const int* __restrict__ srcs, const float* __restrict__ maskA,
               ushort* __restrict__ outb, float* __restrict__ maskB, int n) {
    int w = __builtin_amdgcn_readfirstlane(threadIdx.x >> 6);
    int node = blockIdx.x * 4 + w;
    int lane = threadIdx.x & 63;
    if (node >= n) return;
    float acc = bf2f(hb[node * HD + lane]);
    float m = maskA[node];
    int s = rowptr[node], e = rowptr[node + 1];
    int p = s;
    for (; p + 4 <= e; p += 4) {
        int j0 = srcs[p], j1 = srcs[p + 1], j2 = srcs[p + 2], j3 = srcs[p + 3];
        acc += bf2f(hb[j0 * HD + lane]) + bf2f(hb[j1 * HD + lane])
             + bf2f(hb[j2 * HD + lane]) + bf2f(hb[j3 * HD + lane]);
        m += maskA[j0] + maskA[j1] + maskA[j2] + maskA[j3];
    }
    for (; p < e; ++p) { int j = srcs[p]; acc += bf2f(hb[j * HD + lane]); m += maskA[j]; }
    outb[node * HD + lane] = f2bf(acc);
    if (lane == 0) maskB[node] = (m > 0.f) ? 1.f : 0.f;
}

// ---------------- MFMA dense kernels ----------------
// Layouts (v_mfma_f32_16x16x32_bf16):
//   A frag: row = l&15, k = (l>>4)*8 + j (8 contiguous bf16 -> one b128)
//   B frag: col = l&15, k = (l>>4)*8 + j (use transposed W in LDS)
//   C/D:    col = l&15, row = (l>>4)*4 + reg   [verified layout]
// LDS swizzle: ushort idx = (r*64 + k) ^ ((r&7)<<3)

// MODE 0: layer0 (A-side built from scalar agg outer product); no res/bn2.
// MODE 1: GIN layer: out = bn2(( res + bn1(relu(relu(X@W1+b1)@W2+b2)) )*mask)
template <int MODE>
__global__ __launch_bounds__(256)
void gin_mfma(const float* __restrict__ agg, const ushort* __restrict__ aggb,
              const float* __restrict__ w1f, const float* __restrict__ W1,
              const float* __restrict__ b1, const float* __restrict__ W2,
              const float* __restrict__ b2, const float* __restrict__ bn1,
              const float* __restrict__ res, const float* __restrict__ mask,
              const float* __restrict__ bn2p,
              float* __restrict__ hout, ushort* __restrict__ hbout, int n) {
    __shared__ ushort wt1[4096];
    __shared__ ushort wt2[4096];
    __shared__ ushort z1[4096];  // 4 waves x (16x64)
    int tid = threadIdx.x;
    int l = tid & 63;
    int w = __builtin_amdgcn_readfirstlane(tid >> 6);
    int row0 = blockIdx.x * 64;
    int rbase = row0 + w * 16;
    int lrow = l & 15, lgrp = l >> 4;

    // stage weights transposed+swizzled (bf16)
#pragma unroll
    for (int i = 0; i < 16; ++i) {
        int e = i * 256 + tid;
        int k = e >> 6, c = e & 63;
        int idx = (c * 64 + k) ^ ((c & 7) << 3);
        if (MODE == 1) wt1[idx] = f2bf(W1[e]);
        wt2[idx] = f2bf(W2[e]);
    }
    __syncthreads();

    int zb = w * 1024;
    if (MODE == 0) {
        float w1v = w1f[l], b1v = b1[l];
#pragma unroll
        for (int i = 0; i < 16; ++i) {
            int grow = rbase + i; if (grow > n - 1) grow = n - 1;
            float a = agg[grow];
            float v = fmaxf(a * w1v + b1v, 0.f);
            z1[zb + ((i * 64 + l) ^ ((i & 7) << 3))] = f2bf(v);
        }
    } else {
        int arow = rbase + lrow; if (arow > n - 1) arow = n - 1;
        s16x8 a0 = *(const s16x8*)(aggb + arow * HD + lgrp * 8);
        s16x8 a1 = *(const s16x8*)(aggb + arow * HD + 32 + lgrp * 8);
#pragma unroll
        for (int ct = 0; ct < 4; ++ct) {
            int c = ct * 16 + lrow;
            s16x8 bb0 = *(const s16x8*)&wt1[(c * 64 + lgrp * 8) ^ ((c & 7) << 3)];
            s16x8 bb1 = *(const s16x8*)&wt1[(c * 64 + 32 + lgrp * 8) ^ ((c & 7) << 3)];
            f32x4 acc = {0.f, 0.f, 0.f, 0.f};
            acc = __builtin_amdgcn_mfma_f32_16x16x32_bf16(a0, bb0, acc, 0, 0, 0);
            acc = __builtin_amdgcn_mfma_f32_16x16x32_bf16(a1, bb1, acc, 0, 0, 0);
            float bv1 = b1[c];
#pragma unroll
            for (int r = 0; r < 4; ++r) {
                int rl = lgrp * 4 + r;
                float v = fmaxf(acc[r] + bv1, 0.f);
                z1[zb + ((rl * 64 + c) ^ ((rl & 7) << 3))] = f2bf(v);
            }
        }
    }
    // pass 2: A from wave-local z1 (compiler orders LDS ops within the wave)
    s16x8 a0 = *(const s16x8*)&z1[zb + ((lrow * 64 + lgrp * 8) ^ ((lrow & 7) << 3))];
    s16x8 a1 = *(const s16x8*)&z1[zb + ((lrow * 64 + 32 + lgrp * 8) ^ ((lrow & 7) << 3))];

    float mk[4];
#pragma unroll
    for (int r = 0; r < 4; ++r) {
        int grow = rbase + lgrp * 4 + r; if (grow > n - 1) grow = n - 1;
        mk[r] = mask[grow];
    }

#pragma unroll
    for (int ct = 0; ct < 4; ++ct) {
        int c = ct * 16 + lrow;
        s16x8 bb0 = *(const s16x8*)&wt2[(c * 64 + lgrp * 8) ^ ((c & 7) << 3)];
        s16x8 bb1 = *(const s16x8*)&wt2[(c * 64 + 32 + lgrp * 8) ^ ((c & 7) << 3)];
        f32x4 acc = {0.f, 0.f, 0.f, 0.f};
        acc = __builtin_amdgcn_mfma_f32_16x16x32_bf16(a0, bb0, acc, 0, 0, 0);
        acc = __builtin_amdgcn_mfma_f32_16x16x32_bf16(a1, bb1, acc, 0, 0, 0);
        float g = bn1[c], be = bn1[64 + c], mn = bn1[128 + c], var = bn1[192 + c];
        float A1 = g / sqrtf(var + BN_EPS), C1 = be - mn * A1;
        float A2 = 1.f, C2 = 0.f;
        if (MODE == 1) {
            float g2 = bn2p[c], be2 = bn2p[64 + c], mn2 = bn2p[128 + c], var2 = bn2p[192 + c];
            A2 = g2 / sqrtf(var2 + BN_EPS); C2 = be2 - mn2 * A2;
        }
        float bv2 = b2[c];
#pragma unroll
        for (int r = 0; r < 4; ++r) {
            int rl = lgrp * 4 + r;
            int grow = rbase + rl;
            if (grow < n) {
                int gi = grow * HD + c;
                float v = fmaxf(acc[r] + bv2, 0.f) * A1 + C1;
                if (MODE == 1) v += res[gi];
                v *= mk[r];
                if (MODE == 1) v = v * A2 + C2;
                hout[gi] = v;
                hbout[gi] = f2bf(v);
            }
        }
    }
}

// head: t = bn2(leaky(X@l1w+b1)*mask); hs = leaky(t@l2w+l2b)*mask
__global__ __launch_bounds__(256)
void head_mfma(const ushort* __restrict__ hb, const float* __restrict__ W1,
               const float* __restrict__ b1, const float* __restrict__ mask,
               const float* __restrict__ bn2p, const float* __restrict__ l2w,
               const float* __restrict__ l2b, float* __restrict__ hs, int n) {
    __shared__ ushort wt1[4096];
    int tid = threadIdx.x;
    int l = tid & 63;
    int w = __builtin_amdgcn_readfirstlane(tid >> 6);
    int row0 = blockIdx.x * 64;
    int rbase = row0 + w * 16;
    int lrow = l & 15, lgrp = l >> 4;

#pragma unroll
    for (int i = 0; i < 16; ++i) {
        int e = i * 256 + tid;
        int k = e >> 6, c = e & 63;
        wt1[(c * 64 + k) ^ ((c & 7) << 3)] = f2bf(W1[e]);
    }
    __syncthreads();

    int arow = rbase + lrow; if (arow > n - 1) arow = n - 1;
    s16x8 a0 = *(const s16x8*)(hb + arow * HD + lgrp * 8);
    s16x8 a1 = *(const s16x8*)(hb + arow * HD + 32 + lgrp * 8);

    float mk[4];
#pragma unroll
    for (int r = 0; r < 4; ++r) {
        int grow = rbase + lgrp * 4 + r; if (grow > n - 1) grow = n - 1;
        mk[r] = mask[grow];
    }

    float part[4] = {0.f, 0.f, 0.f, 0.f};
#pragma unroll
    for (int ct = 0; ct < 4; ++ct) {
        int c = ct * 16 + lrow;
        s16x8 bb0 = *(const s16x8*)&wt1[(c * 64 + lgrp * 8) ^ ((c & 7) << 3)];
        s16x8 bb1 = *(const s16x8*)&wt1[(c * 64 + 32 + lgrp * 8) ^ ((c & 7) << 3)];
        f32x4 acc = {0.f, 0.f, 0.f, 0.f};
        acc = __builtin_amdgcn_mfma_f32_16x16x32_bf16(a0, bb0, acc, 0, 0, 0);
        acc = __builtin_amdgcn_mfma_f32_16x16x32_bf16(a1, bb1, acc, 0, 0, 0);
        float g = bn2p[c], be = bn2p[64 + c], mn = bn2p[128 + c], var = bn2p[192 + c];
        float A2 = g / sqrtf(var + BN_EPS), C2 = be - mn * A2;
        float bv = b1[c];
        float w2v = l2w[c];
#pragma unroll
        for (int r = 0; r < 4; ++r) {
            float v = acc[r] + bv;
            v = (v > 0.f) ? v : 0.01f * v;
            v *= mk[r];
            v = v * A2 + C2;
            part[r] += v * w2v;
        }
    }
    float l2b0 = l2b[0];
#pragma unroll
    for (int r = 0; r < 4; ++r) {
        float p = part[r];
        p += __shfl_xor(p, 1, 64);
        p += __shfl_xor(p, 2, 64);
        p += __shfl_xor(p, 4, 64);
        p += __shfl_xor(p, 8, 64);
        int grow = rbase + lgrp * 4 + r;
        if (lrow == 0 && grow < n) {
            float z = p + l2b0;
            z = (z > 0.f) ? z : 0.01f * z;
            hs[grow] = z * mk[r];
        }
    }
}

// ---------------- per-graph stats ----------------

__global__ __launch_bounds__(256)
void graph_stats(const float* __restrict__ hs, const float* __restrict__ deg,
                 const int* __restrict__ gstart, const float* __restrict__ recf,
                 const float* __restrict__ totv, const float* __restrict__ trand,
                 float* __restrict__ gmax, float* __restrict__ gmin,
                 float* __restrict__ gtar) {
    __shared__ float smx[256], smn[256], ssm[256];
    int b = blockIdx.x, tid = threadIdx.x;
    int s = gstart[b], e = gstart[b + 1];
    float mx = -INFINITY, mn = INFINITY, sm = 0.f;
    for (int i = s + tid; i < e; i += 256) {
        float v = hs[i];
        mx = fmaxf(mx, v); mn = fminf(mn, v); sm += deg[i];
    }
    smx[tid] = mx; smn[tid] = mn; ssm[tid] = sm;
    __syncthreads();
    for (int o = 128; o > 0; o >>= 1) {
        if (tid < o) {
            smx[tid] = fmaxf(smx[tid], smx[tid + o]);
            smn[tid] = fminf(smn[tid], smn[tid + o]);
            ssm[tid] += ssm[tid + o];
        }
        __syncthreads();
    }
    if (tid == 0) {
        gmax[b] = smx[0];
        gmin[b] = smn[0];
        float tv = ssm[0] + 1e-6f;
        float feas = recf[b] / totv[b];
        gtar[b] = (trand[b] * feas * 0.85f + 0.1f) * tv;
    }
}

__global__ __launch_bounds__(256)
void k_norm(float* __restrict__ hs, const float* __restrict__ mask,
            const float* __restrict__ x, const int* __restrict__ batch,
            const float* __restrict__ gmax, const float* __restrict__ gmin, int n) {
    int i = blockIdx.x * 256 + threadIdx.x;
    if (i >= n) return;
    int b = batch[i];
    float mn = gmin[b], mx = gmax[b];
    float v = (hs[i] - mn) / ((mx + 1e-6f) - mn);
    float m = mask[i];
    hs[i] = v * m + m * 1e-6f + x[i];
}

// ---------------- 30-iteration scan ----------------

__global__ __launch_bounds__(256)
void scan_iters(const float* __restrict__ hs, const float* __restrict__ deg,
                const float* __restrict__ mask, const int* __restrict__ gstart,
                const float* __restrict__ gtar, float* __restrict__ ga) {
    __shared__ float w1[4], w2[4];
    __shared__ float a_sh;
    int b = blockIdx.x, tid = threadIdx.x;
    int lane = tid & 63, wid = tid >> 6;
    int s = gstart[b], e = gstart[b + 1];
    float target = gtar[b];
    int cnt = e - s;
    float a = 1.f;

    if (cnt <= 2048) {
        float hv[8], dm[8], hdm[8];
        float Sdm = 0.f;
#pragma unroll
        for (int k = 0; k < 8; ++k) {
            int i = s + tid + k * 256;
            float h_ = 0.f, d_ = 0.f, m_ = 0.f;
            if (i < e) { h_ = hs[i]; d_ = deg[i]; m_ = mask[i]; }
            hv[k] = h_;
            float t = d_ * m_;
            dm[k] = t;
            hdm[k] = h_ * t;
            Sdm += t;
        }
        {
            float v = Sdm;
#pragma unroll
            for (int o = 32; o > 0; o >>= 1) v += __shfl_down(v, o, 64);
            if (lane == 0) w1[wid] = v;
            __syncthreads();
            if (tid == 0) a_sh = w1[0] + w1[1] + w1[2] + w1[3];
            __syncthreads();
            Sdm = a_sh;
            __syncthreads();
        }
        for (int it = 0; it < 30; ++it) {
            float t1 = 0.f, t2 = 0.f;
#pragma unroll
            for (int k = 0; k < 8; ++k) {
                float keep = (a * hv[k] < 1.f) ? 1.f : 0.f;
                t1 += dm[k] * keep;
                t2 += hdm[k] * keep;
            }
#pragma unroll
            for (int o = 32; o > 0; o >>= 1) {
                t1 += __shfl_down(t1, o, 64);
                t2 += __shfl_down(t2, o, 64);
            }
            if (lane == 0) { w1[wid] = t1; w2[wid] = t2; }
            __syncthreads();
            if (tid == 0) {
                float dnk = Sdm - (w1[0] + w1[1] + w1[2] + w1[3]);
                float dot = w2[0] + w2[1] + w2[2] + w2[3];
                a_sh = (target - dnk) / (dot + 1e-5f);
            }
            __syncthreads();
            a = a_sh;
        }
    } else {
        __shared__ float s1[256], s2[256];
        for (int it = 0; it < 30; ++it) {
            float dnk = 0.f, dot = 0.f;
            for (int i = s + tid; i < e; i += 256) {
                float hv = hs[i], d = deg[i], m = mask[i];
                float keep = (a * hv < 1.f) ? 1.f : 0.f;
                float km = keep * m;
                dnk += d * (m - km);
                dot += hv * d * km;
            }
            s1[tid] = dnk; s2[tid] = dot;
            __syncthreads();
            for (int o = 128; o > 0; o >>= 1) {
                if (tid < o) { s1[tid] += s1[tid + o]; s2[tid] += s2[tid + o]; }
                __syncthreads();
            }
            if (tid == 0) a_sh = (target - s1[0]) / (s2[0] + 1e-5f);
            __syncthreads();
            a = a_sh;
        }
    }
    if (tid == 0) ga[b] = a;
}

// ---------------- probs + cut ----------------

__global__ __launch_bounds__(256)
void k_probs(const float* __restrict__ hs, const float* __restrict__ mask,
             const float* __restrict__ deg, const int* __restrict__ batch,
             const float* __restrict__ ga, float* __restrict__ out,
             float* __restrict__ cutpad, int n) {
    int i = blockIdx.x * 256 + threadIdx.x;
    bool valid = i < n;
    int b = valid ? batch[i] : 0;
    float contrib = 0.f;
    if (valid) {
        float p = ga[b] * hs[i] * mask[i];
        p = fminf(fmaxf(p, 0.f), 1.f);
        out[i] = p;
        contrib = p * deg[i];
    }
    int b0 = __shfl(b, 0, 64);
    bool uni = __all(b == b0);
    if (uni) {
#pragma unroll
        for (int o = 32; o > 0; o >>= 1) contrib += __shfl_down(contrib, o, 64);
        if ((threadIdx.x & 63) == 0) atomicAdd(&cutpad[b0 * 16], contrib);
    } else if (valid) {
        atomicAdd(&cutpad[b * 16], contrib);
    }
}

__global__ __launch_bounds__(256)
void cut_edges(const int* __restrict__ row, const int* __restrict__ col,
               const int* __restrict__ batch, const float* __restrict__ probs,
               float* __restrict__ cutpad, int E) {
    __shared__ float lc[128];
    int tid = threadIdx.x;
    if (tid < 128) lc[tid] = 0.f;
    __syncthreads();
    for (int e = blockIdx.x * 256 + tid; e < E; e += gridDim.x * 256) {
        int r = row[e], c = col[e];
        float v = probs[r] * probs[c];
        atomicAdd(&lc[batch[r]], v);
    }
    __syncthreads();
    if (tid < 128) {
        float v = lc[tid];
        if (v != 0.f) atomicAdd(&cutpad[tid * 16], -v);
    }
}

__global__ void k_loss(const float* __restrict__ cutpad, float* __restrict__ out, int nidx, int B) {
    __shared__ float sd[128];
    int tid = threadIdx.x;
    sd[tid] = (tid < B) ? cutpad[tid * 16] : 0.f;
    __syncthreads();
    for (int o = 64; o > 0; o >>= 1) {
        if (tid < o) sd[tid] += sd[tid + o];
        __syncthreads();
    }
    if (tid == 0) out[nidx] = sd[0] / (float)B;
}

// ---------------- host ----------------

extern "C" void kernel_launch(void* const* d_in, const int* in_sizes, int n_in,
                              void* d_out, int out_size, void* d_ws, size_t ws_size,
                              hipStream_t stream) {
    const float* x     = (const float*)d_in[0];
    const int*   ei    = (const int*)d_in[1];
    const int*   batch = (const int*)d_in[2];
    const float* recf  = (const float*)d_in[3];
    const float* totv  = (const float*)d_in[4];
    const float* trand = (const float*)d_in[5];
    const float* c1w1  = (const float*)d_in[6];
    const float* c1b1  = (const float*)d_in[7];
    const float* c1w2  = (const float*)d_in[8];
    const float* c1b2  = (const float*)d_in[9];
    const float* c1bn  = (const float*)d_in[10];
    const float* cw1   = (const float*)d_in[11];
    const float* cb1   = (const float*)d_in[12];
    const float* cw2   = (const float*)d_in[13];
    const float* cb2   = (const float*)d_in[14];
    const float* cbn   = (const float*)d_in[15];
    const float* obn   = (const float*)d_in[16];
    const float* l1w   = (const float*)d_in[17];
    const float* l1b   = (const float*)d_in[18];
    const float* bn2   = (const float*)d_in[19];
    const float* l2w   = (const float*)d_in[20];
    const float* l2b   = (const float*)d_in[21];

    int N  = in_sizes[0];
    int E  = in_sizes[1] / 2;
    int B  = in_sizes[3];
    int NL = in_sizes[11] / (HD * HD);
    const int* row = ei;
    const int* col = ei + E;
    int NB = (N + BSZ - 1) >> BSH;

    long NH = (long)N * HD;
    float* ws    = (float*)d_ws;
    float*  h    = ws;                       // f32 [N][64]
    ushort* hb   = (ushort*)(h + NH);        // bf16 [N][64]
    ushort* aggb = hb + NH;                  // bf16 [N][64]
    float* maskA = (float*)(aggb + NH);
    float* maskB = maskA + N;
    float* deg   = maskB + N;
    float* hs    = deg + N;
    float* cutpad = hs + N;
    float* gmax  = cutpad + 2048;
    float* gmin  = gmax + B;
    float* gtar  = gmin + B;
    float* ga    = gtar + B;
    uintptr_t ip = (uintptr_t)(ga + B);
    ip = (ip + 15) & ~(uintptr_t)15;
    int* rowptr  = (int*)ip;
    int* gstart  = rowptr + N + 1;
    int* bc_col  = gstart + (B + 2);
    int* bc_row  = bc_col + 256;
    int* cbase   = bc_row + 256;
    int* rbase   = cbase + 257;
    int* cur_col = rbase + 257;
    int* cur_row = cur_col + 256;
    int* srcs    = cur_row + 256;
    int2* ebuf   = (int2*)hb;   // alias: free until gin_mfma<0> writes hb
    int* rbuf    = (int*)h;     // alias: free until gin_mfma<0> writes h

    dim3 blk(256);
    int gN  = (N + 255) / 256;
    int gMM = (N + 63) / 64;
    int g4  = (N + 3) / 4;
    int gP  = (E + PCH - 1) / PCH;
    int gH  = min((E + 255) / 256, 1024);

    // ---- preprocessing ----
    k_init<<<gN, blk, 0, stream>>>(cutpad, gstart, bc_col, bc_row, N, B);
    k_node_pre<<<gN, blk, 0, stream>>>(batch, gstart, N);
    k_hist<<<gH, blk, 0, stream>>>(row, col, bc_col, bc_row, E);
    scan_mid<<<1, blk, 0, stream>>>(bc_col, bc_row, cbase, rbase, cur_col, cur_row,
                                    gstart, rowptr, N, B, NB, E);
    k_partition<<<gP, blk, 0, stream>>>(row, col, ebuf, rbuf, cur_col, cur_row, E);
    k_bucket_csr<<<NB, blk, 0, stream>>>(ebuf, cbase, x, rowptr, maskA, srcs, N);
    k_bucket_deg<<<NB, blk, 0, stream>>>(rbuf, rbase, deg, N);

    // ---- layer 0 ----
    k_gather_s<<<gN, blk, 0, stream>>>(x, rowptr, srcs, hs, N);
    gin_mfma<0><<<gMM, blk, 0, stream>>>(hs, nullptr, c1w1, nullptr, c1b1,
                                         c1w2, c1b2, c1bn, nullptr, maskA,
                                         nullptr, h, hb, N);

    // ---- GIN loop ----
    for (int i = 0; i < NL; ++i) {
        gather64b<<<g4, blk, 0, stream>>>(hb, rowptr, srcs, maskA, aggb, maskB, N);
        gin_mfma<1><<<gMM, blk, 0, stream>>>(nullptr, aggb, nullptr, cw1 + i * 4096,
                                             cb1 + i * 64, cw2 + i * 4096, cb2 + i * 64,
                                             cbn + i * 256, h, maskB, obn + i * 256,
                                             h, hb, N);
        float* t = maskA; maskA = maskB; maskB = t;
    }

    // ---- head ----
    head_mfma<<<gMM, blk, 0, stream>>>(hb, l1w, l1b, maskA, bn2, l2w, l2b, hs, N);
    graph_stats<<<B, blk, 0, stream>>>(hs, deg, gstart, recf, totv, trand, gmax, gmin, gtar);
    k_norm<<<gN, blk, 0, stream>>>(hs, maskA, x, batch, gmax, gmin, N);
    scan_iters<<<B, blk, 0, stream>>>(hs, deg, maskA, gstart, gtar, ga);

    // ---- probs + cut loss ----
    k_probs<<<gN, blk, 0, stream>>>(hs, maskA, deg, batch, ga, (float*)d_out, cutpad, N);
    cut_edges<<<512, blk, 0, stream>>>(row, col, batch, (float*)d_out, cutpad, E);
    k_loss<<<1, 128, 0, stream>>>(cutpad, (float*)d_out, N, B);
}

// Round 5
// 769.892 us; speedup vs baseline: 2.8318x; 1.0860x over previous
//
#include <hip/hip_runtime.h>
#include <stdint.h>

#define HD 64
#define BN_EPS 1e-5f
#define PCH 4096        // edges per partition block
#define BSH 11          // bucket shift (2048 nodes/bucket)
#define BSZ 2048

typedef __attribute__((ext_vector_type(8))) short s16x8;
typedef __attribute__((ext_vector_type(4))) float f32x4;

__device__ inline ushort f2bf(float f) {
    union { float f; uint u; } v; v.f = f;
    uint u = v.u + 0x7fffu + ((v.u >> 16) & 1u);
    return (ushort)(u >> 16);
}
__device__ inline float bf2f(ushort b) {
    union { uint u; float f; } v; v.u = ((uint)b) << 16; return v.f;
}

// ---------------- init ----------------

__global__ __launch_bounds__(256)
void k_init(float* __restrict__ cutpad, int* __restrict__ gstart,
            int* __restrict__ bc_col, int* __restrict__ bc_row, int n, int B) {
    int i = blockIdx.x * 256 + threadIdx.x;
    if (i < 2048) cutpad[i] = 0.f;
    if (i <= B + 1) gstart[i] = n;  // sentinel
    if (i < 256) { bc_col[i] = 0; bc_row[i] = 0; }
}

__global__ __launch_bounds__(256)
void k_node_pre(const int* __restrict__ batch, int* __restrict__ gstart, int n) {
    int i = blockIdx.x * 256 + threadIdx.x;
    if (i >= n) return;
    int b = batch[i];
    int bp = (i == 0) ? -1 : batch[i - 1];
    if (b != bp) gstart[b] = i;
}

// bucket histograms (col and row), LDS-staged
__global__ __launch_bounds__(256)
void k_hist(const int* __restrict__ row, const int* __restrict__ col,
            int* __restrict__ bc_col, int* __restrict__ bc_row, int E) {
    __shared__ int hc[256], hr[256];
    int tid = threadIdx.x;
    hc[tid] = 0; hr[tid] = 0;
    __syncthreads();
    int stride = gridDim.x * 256;
    for (int e = blockIdx.x * 256 + tid; e < E; e += stride) {
        atomicAdd(&hc[col[e] >> BSH], 1);
        atomicAdd(&hr[row[e] >> BSH], 1);
    }
    __syncthreads();
    if (hc[tid]) atomicAdd(&bc_col[tid], hc[tid]);
    if (hr[tid]) atomicAdd(&bc_row[tid], hr[tid]);
}

// one block: bucket scans (col+row), gstart suffix-min, rowptr[n]
__global__ __launch_bounds__(256)
void scan_mid(const int* __restrict__ bc_col, const int* __restrict__ bc_row,
              int* __restrict__ cbase, int* __restrict__ rbase,
              int* __restrict__ cur_col, int* __restrict__ cur_row,
              int* __restrict__ gstart, int* __restrict__ rowptr,
              int n, int B, int NB, int E) {
    __shared__ int sd[256];
    int tid = threadIdx.x;
    int v = (tid < NB) ? bc_col[tid] : 0;
    sd[tid] = v;
    __syncthreads();
    for (int o = 1; o < 256; o <<= 1) {
        int t = (tid >= o) ? sd[tid - o] : 0;
        __syncthreads(); sd[tid] += t; __syncthreads();
    }
    if (tid < NB) { int ex = sd[tid] - v; cbase[tid] = ex; cur_col[tid] = ex; }
    if (tid == 0) cbase[NB] = E;
    __syncthreads();
    v = (tid < NB) ? bc_row[tid] : 0;
    sd[tid] = v;
    __syncthreads();
    for (int o = 1; o < 256; o <<= 1) {
        int t = (tid >= o) ? sd[tid - o] : 0;
        __syncthreads(); sd[tid] += t; __syncthreads();
    }
    if (tid < NB) { int ex = sd[tid] - v; rbase[tid] = ex; cur_row[tid] = ex; }
    if (tid == 0) rbase[NB] = E;
    __syncthreads();
    int g = (tid <= B) ? gstart[tid] : 0x7fffffff;
    sd[tid] = g;
    __syncthreads();
    for (int o = 1; o < 256; o <<= 1) {
        int t = (tid + o < 256) ? sd[tid + o] : 0x7fffffff;
        __syncthreads(); sd[tid] = min(sd[tid], t); __syncthreads();
    }
    if (tid <= B) gstart[tid] = sd[tid];
    if (tid == 0) rowptr[n] = E;
}

// partition edges into col-buckets (int2) and row-buckets (int)
__global__ __launch_bounds__(256)
void k_partition(const int* __restrict__ row, const int* __restrict__ col,
                 int2* __restrict__ ebuf, int* __restrict__ rbuf,
                 int* __restrict__ cur_col, int* __restrict__ cur_row, int E) {
    __shared__ int hc[256], hr[256], basec[256], baser[256];
    int tid = threadIdx.x;
    int e0 = blockIdx.x * PCH;
    hc[tid] = 0; hr[tid] = 0;
    __syncthreads();
    int myr[16], myc[16];
#pragma unroll
    for (int k = 0; k < 16; ++k) {
        int e = e0 + tid + k * 256;
        if (e < E) {
            myr[k] = row[e]; myc[k] = col[e];
            atomicAdd(&hc[myc[k] >> BSH], 1);
            atomicAdd(&hr[myr[k] >> BSH], 1);
        } else myc[k] = -1;
    }
    __syncthreads();
    if (hc[tid]) basec[tid] = atomicAdd(&cur_col[tid], hc[tid]);
    if (hr[tid]) baser[tid] = atomicAdd(&cur_row[tid], hr[tid]);
    __syncthreads();
    hc[tid] = 0; hr[tid] = 0;
    __syncthreads();
#pragma unroll
    for (int k = 0; k < 16; ++k) {
        if (myc[k] >= 0) {
            int bc = myc[k] >> BSH;
            int pos = basec[bc] + atomicAdd(&hc[bc], 1);
            ebuf[pos] = make_int2(myr[k], myc[k]);
            int br = myr[k] >> BSH;
            int pos2 = baser[br] + atomicAdd(&hr[br], 1);
            rbuf[pos2] = myr[k];
        }
    }
}

// per col-bucket: LDS count + scan -> rowptr/maskA coalesced, srcs via LDS cursors
__global__ __launch_bounds__(256)
void k_bucket_csr(const int2* __restrict__ ebuf, const int* __restrict__ cbase,
                  const float* __restrict__ x, int* __restrict__ rowptr,
                  float* __restrict__ maskA, int* __restrict__ srcs, int n) {
    __shared__ int cnt2[BSZ];
    __shared__ int flg[BSZ];
    __shared__ int ss[256];
    int b = blockIdx.x, tid = threadIdx.x;
    int node0 = b << BSH;
    int e0 = cbase[b], e1 = cbase[b + 1];
#pragma unroll
    for (int k = 0; k < 8; ++k) { cnt2[tid + k * 256] = 0; flg[tid + k * 256] = 0; }
    __syncthreads();
    for (int e = e0 + tid; e < e1; e += 256) {
        int2 rc = ebuf[e];
        int lc = rc.y - node0;
        atomicAdd(&cnt2[lc], 1);
        if (x[rc.x] != 0.f) flg[lc] = 1;  // benign race
    }
    __syncthreads();
    int base = tid * 8;
    int v[8];
#pragma unroll
    for (int k = 0; k < 8; ++k) v[k] = cnt2[base + k];
    int run = 0;
#pragma unroll
    for (int k = 0; k < 8; ++k) { int t = v[k]; v[k] = run; run += t; }
    ss[tid] = run;
    __syncthreads();
    for (int o = 1; o < 256; o <<= 1) {
        int t = (tid >= o) ? ss[tid - o] : 0;
        __syncthreads(); ss[tid] += t; __syncthreads();
    }
    int choff = ss[tid] - run;
#pragma unroll
    for (int k = 0; k < 8; ++k) cnt2[base + k] = v[k] + choff;
    __syncthreads();
#pragma unroll
    for (int k = 0; k < 8; ++k) {
        int idx = tid + k * 256;
        int node = node0 + idx;
        if (node < n) {
            rowptr[node] = e0 + cnt2[idx];
            float own = (x[node] != 0.f) ? 1.f : 0.f;
            maskA[node] = (own != 0.f || flg[idx]) ? 1.f : 0.f;
        }
    }
    __syncthreads();
    for (int e = e0 + tid; e < e1; e += 256) {
        int2 rc = ebuf[e];
        int lc = rc.y - node0;
        int pos = atomicAdd(&cnt2[lc], 1);
        srcs[e0 + pos] = rc.x;
    }
}

// per row-bucket: out-degree in LDS, deg coalesced
__global__ __launch_bounds__(256)
void k_bucket_deg(const int* __restrict__ rbuf, const int* __restrict__ rbase,
                  float* __restrict__ deg, int n) {
    __shared__ int cnt2[BSZ];
    int b = blockIdx.x, tid = threadIdx.x;
    int node0 = b << BSH;
    int e0 = rbase[b], e1 = rbase[b + 1];
#pragma unroll
    for (int k = 0; k < 8; ++k) cnt2[tid + k * 256] = 0;
    __syncthreads();
    for (int e = e0 + tid; e < e1; e += 256)
        atomicAdd(&cnt2[rbuf[e] - node0], 1);
    __syncthreads();
#pragma unroll
    for (int k = 0; k < 8; ++k) {
        int idx = tid + k * 256;
        int node = node0 + idx;
        if (node < n) deg[node] = (float)cnt2[idx];
    }
}

// ---------------- gathers ----------------

__global__ __launch_bounds__(256)
void k_gather_s(const float* __restrict__ x, const int* __restrict__ rowptr,
                const int* __restrict__ srcs, float* __restrict__ aggs, int n) {
    int i = blockIdx.x * 256 + threadIdx.x;
    if (i >= n) return;
    float acc = x[i];
    int s = rowptr[i], e = rowptr[i + 1];
    int p = s;
    for (; p + 4 <= e; p += 4) {
        int j0 = srcs[p], j1 = srcs[p + 1], j2 = srcs[p + 2], j3 = srcs[p + 3];
        acc += x[j0] + x[j1] + x[j2] + x[j3];
    }
    for (; p < e; ++p) acc += x[srcs[p]];
    aggs[i] = acc;
}

// bf16 h-gather + fused mask OR; 8 rows in flight for memory-level parallelism
__global__ __launch_bounds__(256)
void gather64b(const ushort* __restrict__ hb, const int* __restrict__ rowptr,
               const int* __restrict__ srcs, const float* __restrict__ maskA,
               ushort* __restrict__ outb, float* __restrict__ maskB, int n) {
    int w = __builtin_amdgcn_readfirstlane(threadIdx.x >> 6);
    int node = blockIdx.x * 4 + w;
    int lane = threadIdx.x & 63;
    if (node >= n) return;
    float acc = bf2f(hb[node * HD + lane]);
    float m = maskA[node];
    int s = rowptr[node], e = rowptr[node + 1];
    int p = s;
    for (; p + 8 <= e; p += 8) {
        int j0 = srcs[p],     j1 = srcs[p + 1], j2 = srcs[p + 2], j3 = srcs[p + 3];
        int j4 = srcs[p + 4], j5 = srcs[p + 5], j6 = srcs[p + 6], j7 = srcs[p + 7];
        float a0 = bf2f(hb[j0 * HD + lane]);
        float a1 = bf2f(hb[j1 * HD + lane]);
        float a2 = bf2f(hb[j2 * HD + lane]);
        float a3 = bf2f(hb[j3 * HD + lane]);
        float a4 = bf2f(hb[j4 * HD + lane]);
        float a5 = bf2f(hb[j5 * HD + lane]);
        float a6 = bf2f(hb[j6 * HD + lane]);
        float a7 = bf2f(hb[j7 * HD + lane]);
        float m0 = maskA[j0], m1 = maskA[j1], m2 = maskA[j2], m3 = maskA[j3];
        float m4 = maskA[j4], m5 = maskA[j5], m6 = maskA[j6], m7 = maskA[j7];
        acc += ((a0 + a1) + (a2 + a3)) + ((a4 + a5) + (a6 + a7));
        m += ((m0 + m1) + (m2 + m3)) + ((m4 + m5) + (m6 + m7));
    }
    for (; p + 4 <= e; p += 4) {
        int j0 = srcs[p], j1 = srcs[p + 1], j2 = srcs[p + 2], j3 = srcs[p + 3];
        acc += bf2f(hb[j0 * HD + lane]) + bf2f(hb[j1 * HD + lane])
             + bf2f(hb[j2 * HD + lane]) + bf2f(hb[j3 * HD + lane]);
        m += maskA[j0] + maskA[j1] + maskA[j2] + maskA[j3];
    }
    for (; p < e; ++p) { int j = srcs[p]; acc += bf2f(hb[j * HD + lane]); m += maskA[j]; }
    outb[node * HD + lane] = f2bf(acc);
    if (lane == 0) maskB[node] = (m > 0.f) ? 1.f : 0.f;
}

// ---------------- MFMA dense kernels ----------------
// Layouts (v_mfma_f32_16x16x32_bf16):
//   A frag: row = l&15, k = (l>>4)*8 + j ; B frag: col = l&15 (transposed-W LDS)
//   C/D:    col = l&15, row = (l>>4)*4 + reg
// LDS swizzle: ushort idx = (r*64 + k) ^ ((r&7)<<3)

// MODE 0: layer0 (A built from scalar agg outer product); no res/bn2.
// MODE 1: GIN layer; residual read from hb (bf16) IN PLACE, result overwrites hb.
template <int MODE>
__global__ __launch_bounds__(256)
void gin_mfma(const float* __restrict__ agg, const ushort* __restrict__ aggb,
              const float* __restrict__ w1f, const float* __restrict__ W1,
              const float* __restrict__ b1, const float* __restrict__ W2,
              const float* __restrict__ b2, const float* __restrict__ bn1,
              const float* __restrict__ mask, const float* __restrict__ bn2p,
              ushort* __restrict__ hbout, int n) {
    __shared__ ushort wt1[4096];
    __shared__ ushort wt2[4096];
    __shared__ ushort z1[4096];  // 4 waves x (16x64)
    int tid = threadIdx.x;
    int l = tid & 63;
    int w = __builtin_amdgcn_readfirstlane(tid >> 6);
    int row0 = blockIdx.x * 64;
    int rbase = row0 + w * 16;
    int lrow = l & 15, lgrp = l >> 4;

    // stage weights transposed+swizzled (bf16)
#pragma unroll
    for (int i = 0; i < 16; ++i) {
        int e = i * 256 + tid;
        int k = e >> 6, c = e & 63;
        int idx = (c * 64 + k) ^ ((c & 7) << 3);
        if (MODE == 1) wt1[idx] = f2bf(W1[e]);
        wt2[idx] = f2bf(W2[e]);
    }
    __syncthreads();

    int zb = w * 1024;
    if (MODE == 0) {
        float w1v = w1f[l], b1v = b1[l];
#pragma unroll
        for (int i = 0; i < 16; ++i) {
            int grow = rbase + i; if (grow > n - 1) grow = n - 1;
            float a = agg[grow];
            float v = fmaxf(a * w1v + b1v, 0.f);
            z1[zb + ((i * 64 + l) ^ ((i & 7) << 3))] = f2bf(v);
        }
    } else {
        int arow = rbase + lrow; if (arow > n - 1) arow = n - 1;
        s16x8 a0 = *(const s16x8*)(aggb + arow * HD + lgrp * 8);
        s16x8 a1 = *(const s16x8*)(aggb + arow * HD + 32 + lgrp * 8);
#pragma unroll
        for (int ct = 0; ct < 4; ++ct) {
            int c = ct * 16 + lrow;
            s16x8 bb0 = *(const s16x8*)&wt1[(c * 64 + lgrp * 8) ^ ((c & 7) << 3)];
            s16x8 bb1 = *(const s16x8*)&wt1[(c * 64 + 32 + lgrp * 8) ^ ((c & 7) << 3)];
            f32x4 acc = {0.f, 0.f, 0.f, 0.f};
            acc = __builtin_amdgcn_mfma_f32_16x16x32_bf16(a0, bb0, acc, 0, 0, 0);
            acc = __builtin_amdgcn_mfma_f32_16x16x32_bf16(a1, bb1, acc, 0, 0, 0);
            float bv1 = b1[c];
#pragma unroll
            for (int r = 0; r < 4; ++r) {
                int rl = lgrp * 4 + r;
                float v = fmaxf(acc[r] + bv1, 0.f);
                z1[zb + ((rl * 64 + c) ^ ((rl & 7) << 3))] = f2bf(v);
            }
        }
    }
    // pass 2: A from wave-local z1
    s16x8 a0 = *(const s16x8*)&z1[zb + ((lrow * 64 + lgrp * 8) ^ ((lrow & 7) << 3))];
    s16x8 a1 = *(const s16x8*)&z1[zb + ((lrow * 64 + 32 + lgrp * 8) ^ ((lrow & 7) << 3))];

    float mk[4];
#pragma unroll
    for (int r = 0; r < 4; ++r) {
        int grow = rbase + lgrp * 4 + r; if (grow > n - 1) grow = n - 1;
        mk[r] = mask[grow];
    }

#pragma unroll
    for (int ct = 0; ct < 4; ++ct) {
        int c = ct * 16 + lrow;
        s16x8 bb0 = *(const s16x8*)&wt2[(c * 64 + lgrp * 8) ^ ((c & 7) << 3)];
        s16x8 bb1 = *(const s16x8*)&wt2[(c * 64 + 32 + lgrp * 8) ^ ((c & 7) << 3)];
        f32x4 acc = {0.f, 0.f, 0.f, 0.f};
        acc = __builtin_amdgcn_mfma_f32_16x16x32_bf16(a0, bb0, acc, 0, 0, 0);
        acc = __builtin_amdgcn_mfma_f32_16x16x32_bf16(a1, bb1, acc, 0, 0, 0);
        float g = bn1[c], be = bn1[64 + c], mn = bn1[128 + c], var = bn1[192 + c];
        float A1 = g / sqrtf(var + BN_EPS), C1 = be - mn * A1;
        float A2 = 1.f, C2 = 0.f;
        if (MODE == 1) {
            float g2 = bn2p[c], be2 = bn2p[64 + c], mn2 = bn2p[128 + c], var2 = bn2p[192 + c];
            A2 = g2 / sqrtf(var2 + BN_EPS); C2 = be2 - mn2 * A2;
        }
        float bv2 = b2[c];
#pragma unroll
        for (int r = 0; r < 4; ++r) {
            int rl = lgrp * 4 + r;
            int grow = rbase + rl;
            if (grow < n) {
                int gi = grow * HD + c;
                float v = fmaxf(acc[r] + bv2, 0.f) * A1 + C1;
                if (MODE == 1) v += bf2f(hbout[gi]);   // residual (in place)
                v *= mk[r];
                if (MODE == 1) v = v * A2 + C2;
                hbout[gi] = f2bf(v);
            }
        }
    }
}

// head: t = bn2(leaky(X@l1w+b1)*mask); hs = leaky(t@l2w+l2b)*mask
__global__ __launch_bounds__(256)
void head_mfma(const ushort* __restrict__ hb, const float* __restrict__ W1,
               const float* __restrict__ b1, const float* __restrict__ mask,
               const float* __restrict__ bn2p, const float* __restrict__ l2w,
               const float* __restrict__ l2b, float* __restrict__ hs, int n) {
    __shared__ ushort wt1[4096];
    int tid = threadIdx.x;
    int l = tid & 63;
    int w = __builtin_amdgcn_readfirstlane(tid >> 6);
    int row0 = blockIdx.x * 64;
    int rbase = row0 + w * 16;
    int lrow = l & 15, lgrp = l >> 4;

#pragma unroll
    for (int i = 0; i < 16; ++i) {
        int e = i * 256 + tid;
        int k = e >> 6, c = e & 63;
        wt1[(c * 64 + k) ^ ((c & 7) << 3)] = f2bf(W1[e]);
    }
    __syncthreads();

    int arow = rbase + lrow; if (arow > n - 1) arow = n - 1;
    s16x8 a0 = *(const s16x8*)(hb + arow * HD + lgrp * 8);
    s16x8 a1 = *(const s16x8*)(hb + arow * HD + 32 + lgrp * 8);

    float mk[4];
#pragma unroll
    for (int r = 0; r < 4; ++r) {
        int grow = rbase + lgrp * 4 + r; if (grow > n - 1) grow = n - 1;
        mk[r] = mask[grow];
    }

    float part[4] = {0.f, 0.f, 0.f, 0.f};
#pragma unroll
    for (int ct = 0; ct < 4; ++ct) {
        int c = ct * 16 + lrow;
        s16x8 bb0 = *(const s16x8*)&wt1[(c * 64 + lgrp * 8) ^ ((c & 7) << 3)];
        s16x8 bb1 = *(const s16x8*)&wt1[(c * 64 + 32 + lgrp * 8) ^ ((c & 7) << 3)];
        f32x4 acc = {0.f, 0.f, 0.f, 0.f};
        acc = __builtin_amdgcn_mfma_f32_16x16x32_bf16(a0, bb0, acc, 0, 0, 0);
        acc = __builtin_amdgcn_mfma_f32_16x16x32_bf16(a1, bb1, acc, 0, 0, 0);
        float g = bn2p[c], be = bn2p[64 + c], mn = bn2p[128 + c], var = bn2p[192 + c];
        float A2 = g / sqrtf(var + BN_EPS), C2 = be - mn * A2;
        float bv = b1[c];
        float w2v = l2w[c];
#pragma unroll
        for (int r = 0; r < 4; ++r) {
            float v = acc[r] + bv;
            v = (v > 0.f) ? v : 0.01f * v;
            v *= mk[r];
            v = v * A2 + C2;
            part[r] += v * w2v;
        }
    }
    float l2b0 = l2b[0];
#pragma unroll
    for (int r = 0; r < 4; ++r) {
        float p = part[r];
        p += __shfl_xor(p, 1, 64);
        p += __shfl_xor(p, 2, 64);
        p += __shfl_xor(p, 4, 64);
        p += __shfl_xor(p, 8, 64);
        int grow = rbase + lgrp * 4 + r;
        if (lrow == 0 && grow < n) {
            float z = p + l2b0;
            z = (z > 0.f) ? z : 0.01f * z;
            hs[grow] = z * mk[r];
        }
    }
}

// ---------------- per-graph stats ----------------

__global__ __launch_bounds__(256)
void graph_stats(const float* __restrict__ hs, const float* __restrict__ deg,
                 const int* __restrict__ gstart, const float* __restrict__ recf,
                 const float* __restrict__ totv, const float* __restrict__ trand,
                 float* __restrict__ gmax, float* __restrict__ gmin,
                 float* __restrict__ gtar) {
    __shared__ float smx[256], smn[256], ssm[256];
    int b = blockIdx.x, tid = threadIdx.x;
    int s = gstart[b], e = gstart[b + 1];
    float mx = -INFINITY, mn = INFINITY, sm = 0.f;
    for (int i = s + tid; i < e; i += 256) {
        float v = hs[i];
        mx = fmaxf(mx, v); mn = fminf(mn, v); sm += deg[i];
    }
    smx[tid] = mx; smn[tid] = mn; ssm[tid] = sm;
    __syncthreads();
    for (int o = 128; o > 0; o >>= 1) {
        if (tid < o) {
            smx[tid] = fmaxf(smx[tid], smx[tid + o]);
            smn[tid] = fminf(smn[tid], smn[tid + o]);
            ssm[tid] += ssm[tid + o];
        }
        __syncthreads();
    }
    if (tid == 0) {
        gmax[b] = smx[0];
        gmin[b] = smn[0];
        float tv = ssm[0] + 1e-6f;
        float feas = recf[b] / totv[b];
        gtar[b] = (trand[b] * feas * 0.85f + 0.1f) * tv;
    }
}

__global__ __launch_bounds__(256)
void k_norm(float* __restrict__ hs, const float* __restrict__ mask,
            const float* __restrict__ x, const int* __restrict__ batch,
            const float* __restrict__ gmax, const float* __restrict__ gmin, int n) {
    int i = blockIdx.x * 256 + threadIdx.x;
    if (i >= n) return;
    int b = batch[i];
    float mn = gmin[b], mx = gmax[b];
    float v = (hs[i] - mn) / ((mx + 1e-6f) - mn);
    float m = mask[i];
    hs[i] = v * m + m * 1e-6f + x[i];
}

// ---------------- 30-iteration scan ----------------

__global__ __launch_bounds__(256)
void scan_iters(const float* __restrict__ hs, const float* __restrict__ deg,
                const float* __restrict__ mask, const int* __restrict__ gstart,
                const float* __restrict__ gtar, float* __restrict__ ga) {
    __shared__ float w1[4], w2[4];
    __shared__ float a_sh;
    int b = blockIdx.x, tid = threadIdx.x;
    int lane = tid & 63, wid = tid >> 6;
    int s = gstart[b], e = gstart[b + 1];
    float target = gtar[b];
    int cnt = e - s;
    float a = 1.f;

    if (cnt <= 2048) {
        float hv[8], dm[8], hdm[8];
        float Sdm = 0.f;
#pragma unroll
        for (int k = 0; k < 8; ++k) {
            int i = s + tid + k * 256;
            float h_ = 0.f, d_ = 0.f, m_ = 0.f;
            if (i < e) { h_ = hs[i]; d_ = deg[i]; m_ = mask[i]; }
            hv[k] = h_;
            float t = d_ * m_;
            dm[k] = t;
            hdm[k] = h_ * t;
            Sdm += t;
        }
        {
            float v = Sdm;
#pragma unroll
            for (int o = 32; o > 0; o >>= 1) v += __shfl_down(v, o, 64);
            if (lane == 0) w1[wid] = v;
            __syncthreads();
            if (tid == 0) a_sh = w1[0] + w1[1] + w1[2] + w1[3];
            __syncthreads();
            Sdm = a_sh;
            __syncthreads();
        }
        for (int it = 0; it < 30; ++it) {
            float t1 = 0.f, t2 = 0.f;
#pragma unroll
            for (int k = 0; k < 8; ++k) {
                float keep = (a * hv[k] < 1.f) ? 1.f : 0.f;
                t1 += dm[k] * keep;
                t2 += hdm[k] * keep;
            }
#pragma unroll
            for (int o = 32; o > 0; o >>= 1) {
                t1 += __shfl_down(t1, o, 64);
                t2 += __shfl_down(t2, o, 64);
            }
            if (lane == 0) { w1[wid] = t1; w2[wid] = t2; }
            __syncthreads();
            if (tid == 0) {
                float dnk = Sdm - (w1[0] + w1[1] + w1[2] + w1[3]);
                float dot = w2[0] + w2[1] + w2[2] + w2[3];
                a_sh = (target - dnk) / (dot + 1e-5f);
            }
            __syncthreads();
            a = a_sh;
        }
    } else {
        __shared__ float s1[256], s2[256];
        for (int it = 0; it < 30; ++it) {
            float dnk = 0.f, dot = 0.f;
            for (int i = s + tid; i < e; i += 256) {
                float hv = hs[i], d = deg[i], m = mask[i];
                float keep = (a * hv < 1.f) ? 1.f : 0.f;
                float km = keep * m;
                dnk += d * (m - km);
                dot += hv * d * km;
            }
            s1[tid] = dnk; s2[tid] = dot;
            __syncthreads();
            for (int o = 128; o > 0; o >>= 1) {
                if (tid < o) { s1[tid] += s1[tid + o]; s2[tid] += s2[tid + o]; }
                __syncthreads();
            }
            if (tid == 0) a_sh = (target - s1[0]) / (s2[0] + 1e-5f);
            __syncthreads();
            a = a_sh;
        }
    }
    if (tid == 0) ga[b] = a;
}

// ---------------- probs + cut ----------------

__global__ __launch_bounds__(256)
void k_probs(const float* __restrict__ hs, const float* __restrict__ mask,
             const float* __restrict__ deg, const int* __restrict__ batch,
             const float* __restrict__ ga, float* __restrict__ out,
             float* __restrict__ cutpad, int n) {
    int i = blockIdx.x * 256 + threadIdx.x;
    bool valid = i < n;
    int b = valid ? batch[i] : 0;
    float contrib = 0.f;
    if (valid) {
        float p = ga[b] * hs[i] * mask[i];
        p = fminf(fmaxf(p, 0.f), 1.f);
        out[i] = p;
        contrib = p * deg[i];
    }
    int b0 = __shfl(b, 0, 64);
    bool uni = __all(b == b0);
    if (uni) {
#pragma unroll
        for (int o = 32; o > 0; o >>= 1) contrib += __shfl_down(contrib, o, 64);
        if ((threadIdx.x & 63) == 0) atomicAdd(&cutpad[b0 * 16], contrib);
    } else if (valid) {
        atomicAdd(&cutpad[b * 16], contrib);
    }
}

__global__ __launch_bounds__(256)
void cut_edges(const int* __restrict__ row, const int* __restrict__ col,
               const int* __restrict__ batch, const float* __restrict__ probs,
               float* __restrict__ cutpad, int E) {
    __shared__ float lc[128];
    int tid = threadIdx.x;
    if (tid < 128) lc[tid] = 0.f;
    __syncthreads();
    for (int e = blockIdx.x * 256 + tid; e < E; e += gridDim.x * 256) {
        int r = row[e], c = col[e];
        float v = probs[r] * probs[c];
        atomicAdd(&lc[batch[r]], v);
    }
    __syncthreads();
    if (tid < 128) {
        float v = lc[tid];
        if (v != 0.f) atomicAdd(&cutpad[tid * 16], -v);
    }
}

__global__ void k_loss(const float* __restrict__ cutpad, float* __restrict__ out, int nidx, int B) {
    __shared__ float sd[128];
    int tid = threadIdx.x;
    sd[tid] = (tid < B) ? cutpad[tid * 16] : 0.f;
    __syncthreads();
    for (int o = 64; o > 0; o >>= 1) {
        if (tid < o) sd[tid] += sd[tid + o];
        __syncthreads();
    }
    if (tid == 0) out[nidx] = sd[0] / (float)B;
}

// ---------------- host ----------------

extern "C" void kernel_launch(void* const* d_in, const int* in_sizes, int n_in,
                              void* d_out, int out_size, void* d_ws, size_t ws_size,
                              hipStream_t stream) {
    const float* x     = (const float*)d_in[0];
    const int*   ei    = (const int*)d_in[1];
    const int*   batch = (const int*)d_in[2];
    const float* recf  = (const float*)d_in[3];
    const float* totv  = (const float*)d_in[4];
    const float* trand = (const float*)d_in[5];
    const float* c1w1  = (const float*)d_in[6];
    const float* c1b1  = (const float*)d_in[7];
    const float* c1w2  = (const float*)d_in[8];
    const float* c1b2  = (const float*)d_in[9];
    const float* c1bn  = (const float*)d_in[10];
    const float* cw1   = (const float*)d_in[11];
    const float* cb1   = (const float*)d_in[12];
    const float* cw2   = (const float*)d_in[13];
    const float* cb2   = (const float*)d_in[14];
    const float* cbn   = (const float*)d_in[15];
    const float* obn   = (const float*)d_in[16];
    const float* l1w   = (const float*)d_in[17];
    const float* l1b   = (const float*)d_in[18];
    const float* bn2   = (const float*)d_in[19];
    const float* l2w   = (const float*)d_in[20];
    const float* l2b   = (const float*)d_in[21];

    int N  = in_sizes[0];
    int E  = in_sizes[1] / 2;
    int B  = in_sizes[3];
    int NL = in_sizes[11] / (HD * HD);
    const int* row = ei;
    const int* col = ei + E;
    int NB = (N + BSZ - 1) >> BSH;

    long NH = (long)N * HD;
    ushort* hb   = (ushort*)d_ws;            // bf16 [N][64] (hidden state, in-place)
    ushort* aggb = hb + NH;                  // bf16 [N][64] (gather output)
    float* maskA = (float*)(aggb + NH);
    float* maskB = maskA + N;
    float* deg   = maskB + N;
    float* hs    = deg + N;
    float* cutpad = hs + N;
    float* gmax  = cutpad + 2048;
    float* gmin  = gmax + B;
    float* gtar  = gmin + B;
    float* ga    = gtar + B;
    uintptr_t ip = (uintptr_t)(ga + B);
    ip = (ip + 15) & ~(uintptr_t)15;
    int* rowptr  = (int*)ip;
    int* gstart  = rowptr + N + 1;
    int* bc_col  = gstart + (B + 2);
    int* bc_row  = bc_col + 256;
    int* cbase   = bc_row + 256;
    int* rbase   = cbase + 257;
    int* cur_col = rbase + 257;
    int* cur_row = cur_col + 256;
    int* srcs    = cur_row + 256;
    int2* ebuf   = (int2*)hb;    // alias: E*8B == NH*2B; dead once gin_mfma<0> writes hb
    int* rbuf    = (int*)aggb;   // alias: E*4B <= NH*2B; dead once gather64b writes aggb

    dim3 blk(256);
    int gN  = (N + 255) / 256;
    int gMM = (N + 63) / 64;
    int g4  = (N + 3) / 4;
    int gP  = (E + PCH - 1) / PCH;
    int gH  = min((E + 255) / 256, 1024);

    // ---- preprocessing ----
    k_init<<<gN, blk, 0, stream>>>(cutpad, gstart, bc_col, bc_row, N, B);
    k_node_pre<<<gN, blk, 0, stream>>>(batch, gstart, N);
    k_hist<<<gH, blk, 0, stream>>>(row, col, bc_col, bc_row, E);
    scan_mid<<<1, blk, 0, stream>>>(bc_col, bc_row, cbase, rbase, cur_col, cur_row,
                                    gstart, rowptr, N, B, NB, E);
    k_partition<<<gP, blk, 0, stream>>>(row, col, ebuf, rbuf, cur_col, cur_row, E);
    k_bucket_csr<<<NB, blk, 0, stream>>>(ebuf, cbase, x, rowptr, maskA, srcs, N);
    k_bucket_deg<<<NB, blk, 0, stream>>>(rbuf, rbase, deg, N);

    // ---- layer 0 ----
    k_gather_s<<<gN, blk, 0, stream>>>(x, rowptr, srcs, hs, N);
    gin_mfma<0><<<gMM, blk, 0, stream>>>(hs, nullptr, c1w1, nullptr, c1b1,
                                         c1w2, c1b2, c1bn, maskA, nullptr, hb, N);

    // ---- GIN loop ----
    for (int i = 0; i < NL; ++i) {
        gather64b<<<g4, blk, 0, stream>>>(hb, rowptr, srcs, maskA, aggb, maskB, N);
        gin_mfma<1><<<gMM, blk, 0, stream>>>(nullptr, aggb, nullptr, cw1 + i * 4096,
                                             cb1 + i * 64, cw2 + i * 4096, cb2 + i * 64,
                                             cbn + i * 256, maskB, obn + i * 256, hb, N);
        float* t = maskA; maskA = maskB; maskB = t;
    }

    // ---- head ----
    head_mfma<<<gMM, blk, 0, stream>>>(hb, l1w, l1b, maskA, bn2, l2w, l2b, hs, N);
    graph_stats<<<B, blk, 0, stream>>>(hs, deg, gstart, recf, totv, trand, gmax, gmin, gtar);
    k_norm<<<gN, blk, 0, stream>>>(hs, maskA, x, batch, gmax, gmin, N);
    scan_iters<<<B, blk, 0, stream>>>(hs, deg, maskA, gstart, gtar, ga);

    // ---- probs + cut loss ----
    k_probs<<<gN, blk, 0, stream>>>(hs, maskA, deg, batch, ga, (float*)d_out, cutpad, N);
    cut_edges<<<512, blk, 0, stream>>>(row, col, batch, (float*)d_out, cutpad, E);
    k_loss<<<1, 128, 0, stream>>>(cutpad, (float*)d_out, N, B);
}

// Round 6
// 605.714 us; speedup vs baseline: 3.5993x; 1.2710x over previous
//
#include <hip/hip_runtime.h>
#include <stdint.h>

#define HD 64
#define BN_EPS 1e-5f
#define PCH 4096        // edges per partition block
#define BSH 9           // bucket shift (512 nodes/bucket)  [requires N < 2^23, NB <= 512]
#define BSZ 512

typedef __attribute__((ext_vector_type(8))) short s16x8;
typedef __attribute__((ext_vector_type(4))) float f32x4;

__device__ inline ushort f2bf(float f) {
    union { float f; uint u; } v; v.f = f;
    uint u = v.u + 0x7fffu + ((v.u >> 16) & 1u);
    return (ushort)(u >> 16);
}
__device__ inline float bf2f(ushort b) {
    union { uint u; float f; } v; v.u = ((uint)b) << 16; return v.f;
}
__device__ inline float asf(uint u) {
    union { uint u; float f; } v; v.u = u; return v.f;
}

// ---------------- init ----------------

__global__ __launch_bounds__(256)
void k_init(float* __restrict__ cutpad, int* __restrict__ gstart,
            int* __restrict__ bc_col, int* __restrict__ bc_row, int n, int B) {
    int i = blockIdx.x * 256 + threadIdx.x;
    if (i < 2048) cutpad[i] = 0.f;
    if (i <= B + 1) gstart[i] = n;  // sentinel
    if (i < 512) { bc_col[i] = 0; bc_row[i] = 0; }
}

__global__ __launch_bounds__(256)
void k_node_pre(const int* __restrict__ batch, int* __restrict__ gstart, int n) {
    int i = blockIdx.x * 256 + threadIdx.x;
    if (i >= n) return;
    int b = batch[i];
    int bp = (i == 0) ? -1 : batch[i - 1];
    if (b != bp) gstart[b] = i;
}

// bucket histograms (col and row), LDS-staged
__global__ __launch_bounds__(256)
void k_hist(const int* __restrict__ row, const int* __restrict__ col,
            int* __restrict__ bc_col, int* __restrict__ bc_row, int E) {
    __shared__ int hc[512], hr[512];
    int tid = threadIdx.x;
    hc[tid] = 0; hc[tid + 256] = 0; hr[tid] = 0; hr[tid + 256] = 0;
    __syncthreads();
    int stride = gridDim.x * 256;
    for (int e = blockIdx.x * 256 + tid; e < E; e += stride) {
        atomicAdd(&hc[col[e] >> BSH], 1);
        atomicAdd(&hr[row[e] >> BSH], 1);
    }
    __syncthreads();
#pragma unroll
    for (int k = 0; k < 2; ++k) {
        int i = tid + k * 256;
        if (hc[i]) atomicAdd(&bc_col[i], hc[i]);
        if (hr[i]) atomicAdd(&bc_row[i], hr[i]);
    }
}

// one block: bucket scans (col+row, up to 512), gstart suffix-min, rowptr[n]
__global__ __launch_bounds__(256)
void scan_mid(const int* __restrict__ bc_col, const int* __restrict__ bc_row,
              int* __restrict__ cbase, int* __restrict__ rbase,
              int* __restrict__ cur_col, int* __restrict__ cur_row,
              int* __restrict__ gstart, int* __restrict__ rowptr,
              int n, int B, int NB, int E) {
    __shared__ int sd[256];
    int tid = threadIdx.x;
    // col buckets: 2 per thread
    int i0 = tid * 2;
    int v0 = (i0 < NB) ? bc_col[i0] : 0;
    int v1 = (i0 + 1 < NB) ? bc_col[i0 + 1] : 0;
    int s2 = v0 + v1;
    sd[tid] = s2;
    __syncthreads();
    for (int o = 1; o < 256; o <<= 1) {
        int t = (tid >= o) ? sd[tid - o] : 0;
        __syncthreads(); sd[tid] += t; __syncthreads();
    }
    int ex = sd[tid] - s2;
    if (i0 < NB)     { cbase[i0] = ex;          cur_col[i0] = ex; }
    if (i0 + 1 < NB) { cbase[i0 + 1] = ex + v0; cur_col[i0 + 1] = ex + v0; }
    if (tid == 0) cbase[NB] = E;
    __syncthreads();
    // row buckets
    v0 = (i0 < NB) ? bc_row[i0] : 0;
    v1 = (i0 + 1 < NB) ? bc_row[i0 + 1] : 0;
    s2 = v0 + v1;
    sd[tid] = s2;
    __syncthreads();
    for (int o = 1; o < 256; o <<= 1) {
        int t = (tid >= o) ? sd[tid - o] : 0;
        __syncthreads(); sd[tid] += t; __syncthreads();
    }
    ex = sd[tid] - s2;
    if (i0 < NB)     { rbase[i0] = ex;          cur_row[i0] = ex; }
    if (i0 + 1 < NB) { rbase[i0 + 1] = ex + v0; cur_row[i0 + 1] = ex + v0; }
    if (tid == 0) rbase[NB] = E;
    __syncthreads();
    // gstart suffix-min over [0..B] (B < 256)
    int g = (tid <= B) ? gstart[tid] : 0x7fffffff;
    sd[tid] = g;
    __syncthreads();
    for (int o = 1; o < 256; o <<= 1) {
        int t = (tid + o < 256) ? sd[tid + o] : 0x7fffffff;
        __syncthreads(); sd[tid] = min(sd[tid], t); __syncthreads();
    }
    if (tid <= B) gstart[tid] = sd[tid];
    if (tid == 0) rowptr[n] = E;
}

// partition edges into col-buckets (packed uint) and row-buckets (int)
__global__ __launch_bounds__(256)
void k_partition(const int* __restrict__ row, const int* __restrict__ col,
                 uint* __restrict__ ebuf, int* __restrict__ rbuf,
                 int* __restrict__ cur_col, int* __restrict__ cur_row, int E) {
    __shared__ int hc[512], hr[512], basec[512], baser[512];
    int tid = threadIdx.x;
    int e0 = blockIdx.x * PCH;
    hc[tid] = 0; hc[tid + 256] = 0; hr[tid] = 0; hr[tid + 256] = 0;
    __syncthreads();
    int myr[16], myc[16];
#pragma unroll
    for (int k = 0; k < 16; ++k) {
        int e = e0 + tid + k * 256;
        if (e < E) {
            myr[k] = row[e]; myc[k] = col[e];
            atomicAdd(&hc[myc[k] >> BSH], 1);
            atomicAdd(&hr[myr[k] >> BSH], 1);
        } else myc[k] = -1;
    }
    __syncthreads();
#pragma unroll
    for (int k = 0; k < 2; ++k) {
        int i = tid + k * 256;
        if (hc[i]) basec[i] = atomicAdd(&cur_col[i], hc[i]);
        if (hr[i]) baser[i] = atomicAdd(&cur_row[i], hr[i]);
    }
    __syncthreads();
    hc[tid] = 0; hc[tid + 256] = 0; hr[tid] = 0; hr[tid + 256] = 0;
    __syncthreads();
#pragma unroll
    for (int k = 0; k < 16; ++k) {
        if (myc[k] >= 0) {
            int bc = myc[k] >> BSH;
            int pos = basec[bc] + atomicAdd(&hc[bc], 1);
            ebuf[pos] = ((uint)myr[k] << BSH) | (uint)(myc[k] & (BSZ - 1));
            int br = myr[k] >> BSH;
            int pos2 = baser[br] + atomicAdd(&hr[br], 1);
            rbuf[pos2] = myr[k];
        }
    }
}

// per bucket: CSR (count+scan+fill) AND out-degree AND maskA — all LDS-local
__global__ __launch_bounds__(256)
void k_bucket_all(const uint* __restrict__ ebuf, const int* __restrict__ cbase,
                  const int* __restrict__ rbuf, const int* __restrict__ rbase,
                  const float* __restrict__ x, int* __restrict__ rowptr,
                  float* __restrict__ maskA, int* __restrict__ srcs,
                  float* __restrict__ deg, int n) {
    __shared__ int cnt2[BSZ];
    __shared__ int flg[BSZ];
    __shared__ int ss[256];
    int b = blockIdx.x, tid = threadIdx.x;
    int node0 = b << BSH;
    int e0 = cbase[b], e1 = cbase[b + 1];
    cnt2[tid] = 0; cnt2[tid + 256] = 0; flg[tid] = 0; flg[tid + 256] = 0;
    __syncthreads();
    for (int e = e0 + tid; e < e1; e += 256) {
        uint pk = ebuf[e];
        int lc = pk & (BSZ - 1);
        int r = pk >> BSH;
        atomicAdd(&cnt2[lc], 1);
        if (x[r] != 0.f) flg[lc] = 1;  // benign race
    }
    __syncthreads();
    // exclusive scan of cnt2[512], 2 per thread
    int i0 = tid * 2;
    int v0 = cnt2[i0], v1 = cnt2[i0 + 1];
    int s2 = v0 + v1;
    ss[tid] = s2;
    __syncthreads();
    for (int o = 1; o < 256; o <<= 1) {
        int t = (tid >= o) ? ss[tid - o] : 0;
        __syncthreads(); ss[tid] += t; __syncthreads();
    }
    int ex = ss[tid] - s2;
    cnt2[i0] = ex; cnt2[i0 + 1] = ex + v0;
    __syncthreads();
    // coalesced rowptr + maskA
#pragma unroll
    for (int k = 0; k < 2; ++k) {
        int idx = tid + k * 256;
        int node = node0 + idx;
        if (node < n) {
            rowptr[node] = e0 + cnt2[idx];
            float own = (x[node] != 0.f) ? 1.f : 0.f;
            maskA[node] = (own != 0.f || flg[idx]) ? 1.f : 0.f;
        }
    }
    __syncthreads();
    // fill srcs via LDS cursors
    for (int e = e0 + tid; e < e1; e += 256) {
        uint pk = ebuf[e];
        int lc = pk & (BSZ - 1);
        int pos = atomicAdd(&cnt2[lc], 1);
        srcs[e0 + pos] = (int)(pk >> BSH);
    }
    // out-degree from row-bucket (reuse flg)
    __syncthreads();
    flg[tid] = 0; flg[tid + 256] = 0;
    __syncthreads();
    int r0 = rbase[b], r1 = rbase[b + 1];
    for (int e = r0 + tid; e < r1; e += 256)
        atomicAdd(&flg[rbuf[e] - node0], 1);
    __syncthreads();
#pragma unroll
    for (int k = 0; k < 2; ++k) {
        int idx = tid + k * 256;
        int node = node0 + idx;
        if (node < n) deg[node] = (float)flg[idx];
    }
}

// ---------------- gathers ----------------

__global__ __launch_bounds__(256)
void k_gather_s(const float* __restrict__ x, const int* __restrict__ rowptr,
                const int* __restrict__ srcs, float* __restrict__ aggs, int n) {
    int i = blockIdx.x * 256 + threadIdx.x;
    if (i >= n) return;
    float acc = x[i];
    int s = rowptr[i], e = rowptr[i + 1];
    int p = s;
    for (; p + 4 <= e; p += 4) {
        int j0 = srcs[p], j1 = srcs[p + 1], j2 = srcs[p + 2], j3 = srcs[p + 3];
        acc += x[j0] + x[j1] + x[j2] + x[j3];
    }
    for (; p < e; ++p) acc += x[srcs[p]];
    aggs[i] = acc;
}

// bf16 h-gather, half-wave per node (2 channels/lane as uint), + mask OR.
// 2 rows in flight per load instruction, 8-deep unroll -> 16 rows/wave in flight.
__global__ __launch_bounds__(256)
void gather64b(const ushort* __restrict__ hb, const int* __restrict__ rowptr,
               const int* __restrict__ srcs, const float* __restrict__ maskA,
               ushort* __restrict__ outb, float* __restrict__ maskB, int n) {
    int tid = threadIdx.x;
    int sub = tid >> 5;          // 8 half-waves per block
    int hl = tid & 31;           // lane within half-wave
    int node = blockIdx.x * 8 + sub;
    if (node >= n) return;
    long co = hl * 2;
    uint v = *(const uint*)(hb + (long)node * HD + co);
    float accL = asf(v << 16);
    float accH = asf(v & 0xffff0000u);
    float m = maskA[node];
    int s = rowptr[node], e = rowptr[node + 1];
    int p = s;
    for (; p + 8 <= e; p += 8) {
        int j0 = srcs[p],     j1 = srcs[p + 1], j2 = srcs[p + 2], j3 = srcs[p + 3];
        int j4 = srcs[p + 4], j5 = srcs[p + 5], j6 = srcs[p + 6], j7 = srcs[p + 7];
        uint v0 = *(const uint*)(hb + (long)j0 * HD + co);
        uint v1 = *(const uint*)(hb + (long)j1 * HD + co);
        uint v2 = *(const uint*)(hb + (long)j2 * HD + co);
        uint v3 = *(const uint*)(hb + (long)j3 * HD + co);
        uint v4 = *(const uint*)(hb + (long)j4 * HD + co);
        uint v5 = *(const uint*)(hb + (long)j5 * HD + co);
        uint v6 = *(const uint*)(hb + (long)j6 * HD + co);
        uint v7 = *(const uint*)(hb + (long)j7 * HD + co);
        float m0 = maskA[j0], m1 = maskA[j1], m2 = maskA[j2], m3 = maskA[j3];
        float m4 = maskA[j4], m5 = maskA[j5], m6 = maskA[j6], m7 = maskA[j7];
        accL += ((asf(v0 << 16) + asf(v1 << 16)) + (asf(v2 << 16) + asf(v3 << 16)))
              + ((asf(v4 << 16) + asf(v5 << 16)) + (asf(v6 << 16) + asf(v7 << 16)));
        accH += ((asf(v0 & 0xffff0000u) + asf(v1 & 0xffff0000u))
               + (asf(v2 & 0xffff0000u) + asf(v3 & 0xffff0000u)))
              + ((asf(v4 & 0xffff0000u) + asf(v5 & 0xffff0000u))
               + (asf(v6 & 0xffff0000u) + asf(v7 & 0xffff0000u)));
        m += ((m0 + m1) + (m2 + m3)) + ((m4 + m5) + (m6 + m7));
    }
    for (; p + 4 <= e; p += 4) {
        int j0 = srcs[p], j1 = srcs[p + 1], j2 = srcs[p + 2], j3 = srcs[p + 3];
        uint v0 = *(const uint*)(hb + (long)j0 * HD + co);
        uint v1 = *(const uint*)(hb + (long)j1 * HD + co);
        uint v2 = *(const uint*)(hb + (long)j2 * HD + co);
        uint v3 = *(const uint*)(hb + (long)j3 * HD + co);
        accL += (asf(v0 << 16) + asf(v1 << 16)) + (asf(v2 << 16) + asf(v3 << 16));
        accH += (asf(v0 & 0xffff0000u) + asf(v1 & 0xffff0000u))
              + (asf(v2 & 0xffff0000u) + asf(v3 & 0xffff0000u));
        m += maskA[j0] + maskA[j1] + maskA[j2] + maskA[j3];
    }
    for (; p < e; ++p) {
        int j = srcs[p];
        uint vv = *(const uint*)(hb + (long)j * HD + co);
        accL += asf(vv << 16);
        accH += asf(vv & 0xffff0000u);
        m += maskA[j];
    }
    uint o = ((uint)f2bf(accH) << 16) | (uint)f2bf(accL);
    *(uint*)(outb + (long)node * HD + co) = o;
    if (hl == 0) maskB[node] = (m > 0.f) ? 1.f : 0.f;
}

// ---------------- MFMA dense kernels ----------------
// Layouts (v_mfma_f32_16x16x32_bf16):
//   A frag: row = l&15, k = (l>>4)*8 + j ; B frag: col = l&15 (transposed-W LDS)
//   C/D:    col = l&15, row = (l>>4)*4 + reg
// LDS swizzle: ushort idx = (r*64 + k) ^ ((r&7)<<3)

// MODE 0: layer0 (A built from scalar agg outer product); no res/bn2.
// MODE 1: GIN layer; residual read from hb (bf16) IN PLACE, result overwrites hb.
template <int MODE>
__global__ __launch_bounds__(256)
void gin_mfma(const float* __restrict__ agg, const ushort* __restrict__ aggb,
              const float* __restrict__ w1f, const float* __restrict__ W1,
              const float* __restrict__ b1, const float* __restrict__ W2,
              const float* __restrict__ b2, const float* __restrict__ bn1,
              const float* __restrict__ mask, const float* __restrict__ bn2p,
              ushort* __restrict__ hbout, int n) {
    __shared__ ushort wt1[4096];
    __shared__ ushort wt2[4096];
    __shared__ ushort z1[4096];  // 4 waves x (16x64)
    int tid = threadIdx.x;
    int l = tid & 63;
    int w = __builtin_amdgcn_readfirstlane(tid >> 6);
    int row0 = blockIdx.x * 64;
    int rbase = row0 + w * 16;
    int lrow = l & 15, lgrp = l >> 4;

    // stage weights transposed+swizzled (bf16)
#pragma unroll
    for (int i = 0; i < 16; ++i) {
        int e = i * 256 + tid;
        int k = e >> 6, c = e & 63;
        int idx = (c * 64 + k) ^ ((c & 7) << 3);
        if (MODE == 1) wt1[idx] = f2bf(W1[e]);
        wt2[idx] = f2bf(W2[e]);
    }
    __syncthreads();

    int zb = w * 1024;
    if (MODE == 0) {
        float w1v = w1f[l], b1v = b1[l];
#pragma unroll
        for (int i = 0; i < 16; ++i) {
            int grow = rbase + i; if (grow > n - 1) grow = n - 1;
            float a = agg[grow];
            float v = fmaxf(a * w1v + b1v, 0.f);
            z1[zb + ((i * 64 + l) ^ ((i & 7) << 3))] = f2bf(v);
        }
    } else {
        int arow = rbase + lrow; if (arow > n - 1) arow = n - 1;
        s16x8 a0 = *(const s16x8*)(aggb + arow * HD + lgrp * 8);
        s16x8 a1 = *(const s16x8*)(aggb + arow * HD + 32 + lgrp * 8);
#pragma unroll
        for (int ct = 0; ct < 4; ++ct) {
            int c = ct * 16 + lrow;
            s16x8 bb0 = *(const s16x8*)&wt1[(c * 64 + lgrp * 8) ^ ((c & 7) << 3)];
            s16x8 bb1 = *(const s16x8*)&wt1[(c * 64 + 32 + lgrp * 8) ^ ((c & 7) << 3)];
            f32x4 acc = {0.f, 0.f, 0.f, 0.f};
            acc = __builtin_amdgcn_mfma_f32_16x16x32_bf16(a0, bb0, acc, 0, 0, 0);
            acc = __builtin_amdgcn_mfma_f32_16x16x32_bf16(a1, bb1, acc, 0, 0, 0);
            float bv1 = b1[c];
#pragma unroll
            for (int r = 0; r < 4; ++r) {
                int rl = lgrp * 4 + r;
                float v = fmaxf(acc[r] + bv1, 0.f);
                z1[zb + ((rl * 64 + c) ^ ((rl & 7) << 3))] = f2bf(v);
            }
        }
    }
    // pass 2: A from wave-local z1
    s16x8 a0 = *(const s16x8*)&z1[zb + ((lrow * 64 + lgrp * 8) ^ ((lrow & 7) << 3))];
    s16x8 a1 = *(const s16x8*)&z1[zb + ((lrow * 64 + 32 + lgrp * 8) ^ ((lrow & 7) << 3))];

    float mk[4];
#pragma unroll
    for (int r = 0; r < 4; ++r) {
        int grow = rbase + lgrp * 4 + r; if (grow > n - 1) grow = n - 1;
        mk[r] = mask[grow];
    }

#pragma unroll
    for (int ct = 0; ct < 4; ++ct) {
        int c = ct * 16 + lrow;
        s16x8 bb0 = *(const s16x8*)&wt2[(c * 64 + lgrp * 8) ^ ((c & 7) << 3)];
        s16x8 bb1 = *(const s16x8*)&wt2[(c * 64 + 32 + lgrp * 8) ^ ((c & 7) << 3)];
        f32x4 acc = {0.f, 0.f, 0.f, 0.f};
        acc = __builtin_amdgcn_mfma_f32_16x16x32_bf16(a0, bb0, acc, 0, 0, 0);
        acc = __builtin_amdgcn_mfma_f32_16x16x32_bf16(a1, bb1, acc, 0, 0, 0);
        float g = bn1[c], be = bn1[64 + c], mn = bn1[128 + c], var = bn1[192 + c];
        float A1 = g / sqrtf(var + BN_EPS), C1 = be - mn * A1;
        float A2 = 1.f, C2 = 0.f;
        if (MODE == 1) {
            float g2 = bn2p[c], be2 = bn2p[64 + c], mn2 = bn2p[128 + c], var2 = bn2p[192 + c];
            A2 = g2 / sqrtf(var2 + BN_EPS); C2 = be2 - mn2 * A2;
        }
        float bv2 = b2[c];
#pragma unroll
        for (int r = 0; r < 4; ++r) {
            int rl = lgrp * 4 + r;
            int grow = rbase + rl;
            if (grow < n) {
                int gi = grow * HD + c;
                float v = fmaxf(acc[r] + bv2, 0.f) * A1 + C1;
                if (MODE == 1) v += bf2f(hbout[gi]);   // residual (in place)
                v *= mk[r];
                if (MODE == 1) v = v * A2 + C2;
                hbout[gi] = f2bf(v);
            }
        }
    }
}

// head: t = bn2(leaky(X@l1w+b1)*mask); hs = leaky(t@l2w+l2b)*mask
__global__ __launch_bounds__(256)
void head_mfma(const ushort* __restrict__ hb, const float* __restrict__ W1,
               const float* __restrict__ b1, const float* __restrict__ mask,
               const float* __restrict__ bn2p, const float* __restrict__ l2w,
               const float* __restrict__ l2b, float* __restrict__ hs, int n) {
    __shared__ ushort wt1[4096];
    int tid = threadIdx.x;
    int l = tid & 63;
    int w = __builtin_amdgcn_readfirstlane(tid >> 6);
    int row0 = blockIdx.x * 64;
    int rbase = row0 + w * 16;
    int lrow = l & 15, lgrp = l >> 4;

#pragma unroll
    for (int i = 0; i < 16; ++i) {
        int e = i * 256 + tid;
        int k = e >> 6, c = e & 63;
        wt1[(c * 64 + k) ^ ((c & 7) << 3)] = f2bf(W1[e]);
    }
    __syncthreads();

    int arow = rbase + lrow; if (arow > n - 1) arow = n - 1;
    s16x8 a0 = *(const s16x8*)(hb + arow * HD + lgrp * 8);
    s16x8 a1 = *(const s16x8*)(hb + arow * HD + 32 + lgrp * 8);

    float mk[4];
#pragma unroll
    for (int r = 0; r < 4; ++r) {
        int grow = rbase + lgrp * 4 + r; if (grow > n - 1) grow = n - 1;
        mk[r] = mask[grow];
    }

    float part[4] = {0.f, 0.f, 0.f, 0.f};
#pragma unroll
    for (int ct = 0; ct < 4; ++ct) {
        int c = ct * 16 + lrow;
        s16x8 bb0 = *(const s16x8*)&wt1[(c * 64 + lgrp * 8) ^ ((c & 7) << 3)];
        s16x8 bb1 = *(const s16x8*)&wt1[(c * 64 + 32 + lgrp * 8) ^ ((c & 7) << 3)];
        f32x4 acc = {0.f, 0.f, 0.f, 0.f};
        acc = __builtin_amdgcn_mfma_f32_16x16x32_bf16(a0, bb0, acc, 0, 0, 0);
        acc = __builtin_amdgcn_mfma_f32_16x16x32_bf16(a1, bb1, acc, 0, 0, 0);
        float g = bn2p[c], be = bn2p[64 + c], mn = bn2p[128 + c], var = bn2p[192 + c];
        float A2 = g / sqrtf(var + BN_EPS), C2 = be - mn * A2;
        float bv = b1[c];
        float w2v = l2w[c];
#pragma unroll
        for (int r = 0; r < 4; ++r) {
            float v = acc[r] + bv;
            v = (v > 0.f) ? v : 0.01f * v;
            v *= mk[r];
            v = v * A2 + C2;
            part[r] += v * w2v;
        }
    }
    float l2b0 = l2b[0];
#pragma unroll
    for (int r = 0; r < 4; ++r) {
        float p = part[r];
        p += __shfl_xor(p, 1, 64);
        p += __shfl_xor(p, 2, 64);
        p += __shfl_xor(p, 4, 64);
        p += __shfl_xor(p, 8, 64);
        int grow = rbase + lgrp * 4 + r;
        if (lrow == 0 && grow < n) {
            float z = p + l2b0;
            z = (z > 0.f) ? z : 0.01f * z;
            hs[grow] = z * mk[r];
        }
    }
}

// ---------------- per-graph stats ----------------

__global__ __launch_bounds__(256)
void graph_stats(const float* __restrict__ hs, const float* __restrict__ deg,
                 const int* __restrict__ gstart, const float* __restrict__ recf,
                 const float* __restrict__ totv, const float* __restrict__ trand,
                 float* __restrict__ gmax, float* __restrict__ gmin,
                 float* __restrict__ gtar) {
    __shared__ float smx[256], smn[256], ssm[256];
    int b = blockIdx.x, tid = threadIdx.x;
    int s = gstart[b], e = gstart[b + 1];
    float mx = -INFINITY, mn = INFINITY, sm = 0.f;
    for (int i = s + tid; i < e; i += 256) {
        float v = hs[i];
        mx = fmaxf(mx, v); mn = fminf(mn, v); sm += deg[i];
    }
    smx[tid] = mx; smn[tid] = mn; ssm[tid] = sm;
    __syncthreads();
    for (int o = 128; o > 0; o >>= 1) {
        if (tid < o) {
            smx[tid] = fmaxf(smx[tid], smx[tid + o]);
            smn[tid] = fminf(smn[tid], smn[tid + o]);
            ssm[tid] += ssm[tid + o];
        }
        __syncthreads();
    }
    if (tid == 0) {
        gmax[b] = smx[0];
        gmin[b] = smn[0];
        float tv = ssm[0] + 1e-6f;
        float feas = recf[b] / totv[b];
        gtar[b] = (trand[b] * feas * 0.85f + 0.1f) * tv;
    }
}

__global__ __launch_bounds__(256)
void k_norm(float* __restrict__ hs, const float* __restrict__ mask,
            const float* __restrict__ x, const int* __restrict__ batch,
            const float* __restrict__ gmax, const float* __restrict__ gmin, int n) {
    int i = blockIdx.x * 256 + threadIdx.x;
    if (i >= n) return;
    int b = batch[i];
    float mn = gmin[b], mx = gmax[b];
    float v = (hs[i] - mn) / ((mx + 1e-6f) - mn);
    float m = mask[i];
    hs[i] = v * m + m * 1e-6f + x[i];
}

// ---------------- 30-iteration scan ----------------

__global__ __launch_bounds__(256)
void scan_iters(const float* __restrict__ hs, const float* __restrict__ deg,
                const float* __restrict__ mask, const int* __restrict__ gstart,
                const float* __restrict__ gtar, float* __restrict__ ga) {
    __shared__ float w1[4], w2[4];
    __shared__ float a_sh;
    int b = blockIdx.x, tid = threadIdx.x;
    int lane = tid & 63, wid = tid >> 6;
    int s = gstart[b], e = gstart[b + 1];
    float target = gtar[b];
    int cnt = e - s;
    float a = 1.f;

    if (cnt <= 2048) {
        float hv[8], dm[8], hdm[8];
        float Sdm = 0.f;
#pragma unroll
        for (int k = 0; k < 8; ++k) {
            int i = s + tid + k * 256;
            float h_ = 0.f, d_ = 0.f, m_ = 0.f;
            if (i < e) { h_ = hs[i]; d_ = deg[i]; m_ = mask[i]; }
            hv[k] = h_;
            float t = d_ * m_;
            dm[k] = t;
            hdm[k] = h_ * t;
            Sdm += t;
        }
        {
            float v = Sdm;
#pragma unroll
            for (int o = 32; o > 0; o >>= 1) v += __shfl_down(v, o, 64);
            if (lane == 0) w1[wid] = v;
            __syncthreads();
            if (tid == 0) a_sh = w1[0] + w1[1] + w1[2] + w1[3];
            __syncthreads();
            Sdm = a_sh;
            __syncthreads();
        }
        for (int it = 0; it < 30; ++it) {
            float t1 = 0.f, t2 = 0.f;
#pragma unroll
            for (int k = 0; k < 8; ++k) {
                float keep = (a * hv[k] < 1.f) ? 1.f : 0.f;
                t1 += dm[k] * keep;
                t2 += hdm[k] * keep;
            }
#pragma unroll
            for (int o = 32; o > 0; o >>= 1) {
                t1 += __shfl_down(t1, o, 64);
                t2 += __shfl_down(t2, o, 64);
            }
            if (lane == 0) { w1[wid] = t1; w2[wid] = t2; }
            __syncthreads();
            if (tid == 0) {
                float dnk = Sdm - (w1[0] + w1[1] + w1[2] + w1[3]);
                float dot = w2[0] + w2[1] + w2[2] + w2[3];
                a_sh = (target - dnk) / (dot + 1e-5f);
            }
            __syncthreads();
            a = a_sh;
        }
    } else {
        __shared__ float s1[256], s2[256];
        for (int it = 0; it < 30; ++it) {
            float dnk = 0.f, dot = 0.f;
            for (int i = s + tid; i < e; i += 256) {
                float hv = hs[i], d = deg[i], m = mask[i];
                float keep = (a * hv < 1.f) ? 1.f : 0.f;
                float km = keep * m;
                dnk += d * (m - km);
                dot += hv * d * km;
            }
            s1[tid] = dnk; s2[tid] = dot;
            __syncthreads();
            for (int o = 128; o > 0; o >>= 1) {
                if (tid < o) { s1[tid] += s1[tid + o]; s2[tid] += s2[tid + o]; }
                __syncthreads();
            }
            if (tid == 0) a_sh = (target - s1[0]) / (s2[0] + 1e-5f);
            __syncthreads();
            a = a_sh;
        }
    }
    if (tid == 0) ga[b] = a;
}

// ---------------- probs + cut ----------------

__global__ __launch_bounds__(256)
void k_probs(const float* __restrict__ hs, const float* __restrict__ mask,
             const float* __restrict__ deg, const int* __restrict__ batch,
             const float* __restrict__ ga, float* __restrict__ out,
             float* __restrict__ cutpad, int n) {
    int i = blockIdx.x * 256 + threadIdx.x;
    bool valid = i < n;
    int b = valid ? batch[i] : 0;
    float contrib = 0.f;
    if (valid) {
        float p = ga[b] * hs[i] * mask[i];
        p = fminf(fmaxf(p, 0.f), 1.f);
        out[i] = p;
        contrib = p * deg[i];
    }
    int b0 = __shfl(b, 0, 64);
    bool uni = __all(b == b0);
    if (uni) {
#pragma unroll
        for (int o = 32; o > 0; o >>= 1) contrib += __shfl_down(contrib, o, 64);
        if ((threadIdx.x & 63) == 0) atomicAdd(&cutpad[b0 * 16], contrib);
    } else if (valid) {
        atomicAdd(&cutpad[b * 16], contrib);
    }
}

__global__ __launch_bounds__(256)
void cut_edges(const int* __restrict__ row, const int* __restrict__ col,
               const int* __restrict__ batch, const float* __restrict__ probs,
               float* __restrict__ cutpad, int E) {
    __shared__ float lc[128];
    int tid = threadIdx.x;
    if (tid < 128) lc[tid] = 0.f;
    __syncthreads();
    for (int e = blockIdx.x * 256 + tid; e < E; e += gridDim.x * 256) {
        int r = row[e], c = col[e];
        float v = probs[r] * probs[c];
        atomicAdd(&lc[batch[r]], v);
    }
    __syncthreads();
    if (tid < 128) {
        float v = lc[tid];
        if (v != 0.f) atomicAdd(&cutpad[tid * 16], -v);
    }
}

__global__ void k_loss(const float* __restrict__ cutpad, float* __restrict__ out, int nidx, int B) {
    __shared__ float sd[128];
    int tid = threadIdx.x;
    sd[tid] = (tid < B) ? cutpad[tid * 16] : 0.f;
    __syncthreads();
    for (int o = 64; o > 0; o >>= 1) {
        if (tid < o) sd[tid] += sd[tid + o];
        __syncthreads();
    }
    if (tid == 0) out[nidx] = sd[0] / (float)B;
}

// ---------------- host ----------------

extern "C" void kernel_launch(void* const* d_in, const int* in_sizes, int n_in,
                              void* d_out, int out_size, void* d_ws, size_t ws_size,
                              hipStream_t stream) {
    const float* x     = (const float*)d_in[0];
    const int*   ei    = (const int*)d_in[1];
    const int*   batch = (const int*)d_in[2];
    const float* recf  = (const float*)d_in[3];
    const float* totv  = (const float*)d_in[4];
    const float* trand = (const float*)d_in[5];
    const float* c1w1  = (const float*)d_in[6];
    const float* c1b1  = (const float*)d_in[7];
    const float* c1w2  = (const float*)d_in[8];
    const float* c1b2  = (const float*)d_in[9];
    const float* c1bn  = (const float*)d_in[10];
    const float* cw1   = (const float*)d_in[11];
    const float* cb1   = (const float*)d_in[12];
    const float* cw2   = (const float*)d_in[13];
    const float* cb2   = (const float*)d_in[14];
    const float* cbn   = (const float*)d_in[15];
    const float* obn   = (const float*)d_in[16];
    const float* l1w   = (const float*)d_in[17];
    const float* l1b   = (const float*)d_in[18];
    const float* bn2   = (const float*)d_in[19];
    const float* l2w   = (const float*)d_in[20];
    const float* l2b   = (const float*)d_in[21];

    int N  = in_sizes[0];
    int E  = in_sizes[1] / 2;
    int B  = in_sizes[3];
    int NL = in_sizes[11] / (HD * HD);
    const int* row = ei;
    const int* col = ei + E;
    int NB = (N + BSZ - 1) >> BSH;   // 391 for N=200000 (requires NB<=512)

    long NH = (long)N * HD;
    ushort* hb   = (ushort*)d_ws;            // bf16 [N][64] (hidden state, in-place)
    ushort* aggb = hb + NH;                  // bf16 [N][64] (gather output)
    float* maskA = (float*)(aggb + NH);
    float* maskB = maskA + N;
    float* deg   = maskB + N;
    float* hs    = deg + N;
    float* cutpad = hs + N;
    float* gmax  = cutpad + 2048;
    float* gmin  = gmax + B;
    float* gtar  = gmin + B;
    float* ga    = gtar + B;
    uintptr_t ip = (uintptr_t)(ga + B);
    ip = (ip + 15) & ~(uintptr_t)15;
    int* rowptr  = (int*)ip;
    int* gstart  = rowptr + N + 1;
    int* bc_col  = gstart + (B + 2);
    int* bc_row  = bc_col + 512;
    int* cbase   = bc_row + 512;
    int* rbase   = cbase + 513;
    int* cur_col = rbase + 513;
    int* cur_row = cur_col + 512;
    int* srcs    = cur_row + 512;
    uint* ebuf   = (uint*)hb;    // alias: E*4B <= NH*2B; dead once gin_mfma<0> writes hb
    int* rbuf    = (int*)aggb;   // alias: E*4B <= NH*2B; dead once gather64b writes aggb

    dim3 blk(256);
    int gN  = (N + 255) / 256;
    int gMM = (N + 63) / 64;
    int g8  = (N + 7) / 8;
    int gP  = (E + PCH - 1) / PCH;
    int gH  = min((E + 255) / 256, 1024);

    // ---- preprocessing ----
    k_init<<<gN, blk, 0, stream>>>(cutpad, gstart, bc_col, bc_row, N, B);
    k_node_pre<<<gN, blk, 0, stream>>>(batch, gstart, N);
    k_hist<<<gH, blk, 0, stream>>>(row, col, bc_col, bc_row, E);
    scan_mid<<<1, blk, 0, stream>>>(bc_col, bc_row, cbase, rbase, cur_col, cur_row,
                                    gstart, rowptr, N, B, NB, E);
    k_partition<<<gP, blk, 0, stream>>>(row, col, ebuf, rbuf, cur_col, cur_row, E);
    k_bucket_all<<<NB, blk, 0, stream>>>(ebuf, cbase, rbuf, rbase, x, rowptr,
                                         maskA, srcs, deg, N);

    // ---- layer 0 ----
    k_gather_s<<<gN, blk, 0, stream>>>(x, rowptr, srcs, hs, N);
    gin_mfma<0><<<gMM, blk, 0, stream>>>(hs, nullptr, c1w1, nullptr, c1b1,
                                         c1w2, c1b2, c1bn, maskA, nullptr, hb, N);

    // ---- GIN loop ----
    for (int i = 0; i < NL; ++i) {
        gather64b<<<g8, blk, 0, stream>>>(hb, rowptr, srcs, maskA, aggb, maskB, N);
        gin_mfma<1><<<gMM, blk, 0, stream>>>(nullptr, aggb, nullptr, cw1 + i * 4096,
                                             cb1 + i * 64, cw2 + i * 4096, cb2 + i * 64,
                                             cbn + i * 256, maskB, obn + i * 256, hb, N);
        float* t = maskA; maskA = maskB; maskB = t;
    }

    // ---- head ----
    head_mfma<<<gMM, blk, 0, stream>>>(hb, l1w, l1b, maskA, bn2, l2w, l2b, hs, N);
    graph_stats<<<B, blk, 0, stream>>>(hs, deg, gstart, recf, totv, trand, gmax, gmin, gtar);
    k_norm<<<gN, blk, 0, stream>>>(hs, maskA, x, batch, gmax, gmin, N);
    scan_iters<<<B, blk, 0, stream>>>(hs, deg, maskA, gstart, gtar, ga);

    // ---- probs + cut loss ----
    k_probs<<<gN, blk, 0, stream>>>(hs, maskA, deg, batch, ga, (float*)d_out, cutpad, N);
    cut_edges<<<512, blk, 0, stream>>>(row, col, batch, (float*)d_out, cutpad, E);
    k_loss<<<1, 128, 0, stream>>>(cutpad, (float*)d_out, N, B);
}